// Round 28
// baseline (2002.764 us; speedup 1.0000x reference)
//
#include <hip/hip_runtime.h>
#include <hip/hip_bf16.h>
#include <math.h>

// ---------------------------------------------------------------- constants
#define BB 2
#define TT 1024
#define DD 1024
#define HH 16
#define KVH 4
#define HDIM 64
#define VV 32768
#define DFF 4096
#define CH 32    // gdn scan chunk (steps staged in LDS per buffer)
#define SEGL 128 // gdn segmented-scan segment length (8 segments)

#define ACT_NONE 0
#define ACT_RELU2 1
#define ACT_SILU 2
#define ACT_SIG 3

typedef __attribute__((ext_vector_type(8))) short short8v;
typedef __attribute__((ext_vector_type(4))) float f32x4;

__device__ inline ushort f2bf(float f) {
  uint u = __float_as_uint(f);
  uint r = u + 0x7FFFu + ((u >> 16) & 1u);
  return (ushort)(r >> 16);
}
__device__ inline uint pack2(float lo, float hi) {
  return (uint)f2bf(lo) | ((uint)f2bf(hi) << 16);
}

// 4-lane (quad) sum via DPP quad_perm: xor1 (0xB1) then xor2 (0x4E). VALU-speed.
__device__ inline float qadd4(float x) {
  float y = __int_as_float(__builtin_amdgcn_update_dpp(
      0, __float_as_int(x), 0xB1, 0xF, 0xF, true));
  x += y;
  float z = __int_as_float(__builtin_amdgcn_update_dpp(
      0, __float_as_int(x), 0x4E, 0xF, 0xF, true));
  return x + z;
}

// async global->LDS, 16B/lane: dst = wave-uniform LDS base + lane*16
__device__ inline void gl_lds16(const void* g, void* l) {
  __builtin_amdgcn_global_load_lds(
      (const __attribute__((address_space(1))) void*)g,
      (__attribute__((address_space(3))) void*)l, 16, 0, 0);
}

// ---------------------------------------------------------------- f32 -> bf16 bulk convert
__global__ __launch_bounds__(256) void cvt_bf_k(const float* __restrict__ src,
                                                ushort* __restrict__ dst, int n8) {
  for (int i = blockIdx.x * 256 + threadIdx.x; i < n8; i += gridDim.x * 256) {
    const float4 a = *reinterpret_cast<const float4*>(src + (size_t)i * 8);
    const float4 b = *reinterpret_cast<const float4*>(src + (size_t)i * 8 + 4);
    uint4 o;
    o.x = pack2(a.x, a.y); o.y = pack2(a.z, a.w);
    o.z = pack2(b.x, b.y); o.w = pack2(b.z, b.w);
    *reinterpret_cast<uint4*>(dst + (size_t)i * 8) = o;
  }
}

// ---------------------------------------------------------------- V transpose+convert: vtb[b][kvh][d][t] = bf16(vb[b][t][kvh*64+d])
__global__ __launch_bounds__(256) void cvt_vt_k(const float* __restrict__ vb,
                                                ushort* __restrict__ vtb) {
  int idx = blockIdx.x * 256 + threadIdx.x;   // B*KVH*64*1024 = 524288
  int t = idx & 1023;
  int rest = idx >> 10;
  int d = rest & 63;
  int bk = rest >> 6;        // b*KVH + kvh
  int b = bk >> 2, kvh = bk & 3;
  float v = vb[((size_t)(b * TT + t)) * 256 + kvh * 64 + d];
  vtb[idx] = f2bf(v);
}

// ---------------------------------------------------------------- rope tables
__global__ __launch_bounds__(256) void rope_tab_k(float* __restrict__ cosT,
                                                  float* __restrict__ sinT) {
  int idx = blockIdx.x * 256 + threadIdx.x;   // T*32 = 32768 total
  int t = idx >> 5, j = idx & 31;
  float inv = 1.0f / powf(10000.0f, (float)(2 * j) * (1.0f / 64.0f));
  float fr = (float)t * inv;
  cosT[idx] = cosf(fr);
  sinT[idx] = sinf(fr);
}

// ---------------------------------------------------------------- embedding gather
__global__ __launch_bounds__(256) void embed_k(const int* __restrict__ tok,
                                               const float* __restrict__ emb,
                                               float* __restrict__ X) {
  int row = blockIdx.x;          // B*T rows
  int tid = threadIdx.x;
  int tk = tok[row];
  float4 v = *reinterpret_cast<const float4*>(emb + (size_t)tk * DD + tid * 4);
  *reinterpret_cast<float4*>(X + (size_t)row * DD + tid * 4) = v;
}

// ---------------------------------------------------------------- rmsnorm over D=1024 (+ optional bf16 copy)
__global__ __launch_bounds__(256) void rmsnorm_k(const float* __restrict__ in,
                                                 float* __restrict__ out,
                                                 ushort* __restrict__ outb) {
  int row = blockIdx.x;
  int tid = threadIdx.x;
  const float* p = in + (size_t)row * DD;
  float4 v = *reinterpret_cast<const float4*>(p + tid * 4);
  float ss = v.x * v.x + v.y * v.y + v.z * v.z + v.w * v.w;
#pragma unroll
  for (int m = 1; m < 64; m <<= 1) ss += __shfl_xor(ss, m, 64);
  __shared__ float wsum[4];
  int wid = tid >> 6, lane = tid & 63;
  if (lane == 0) wsum[wid] = ss;
  __syncthreads();
  float tot = wsum[0] + wsum[1] + wsum[2] + wsum[3];
  float sc = rsqrtf(tot * (1.0f / 1024.0f) + 1e-6f);
  float4 o;
  o.x = v.x * sc; o.y = v.y * sc; o.z = v.z * sc; o.w = v.w * sc;
  *reinterpret_cast<float4*>(out + (size_t)row * DD + tid * 4) = o;
  if (outb) {
    uint2 t; t.x = pack2(o.x, o.y); t.y = pack2(o.z, o.w);
    *reinterpret_cast<uint2*>(outb + (size_t)row * DD + tid * 4) = t;
  }
}

// ---------------------------------------------------------------- MFMA bf16 GEMM: C = [res +] act(A @ W^T)
// swapg: 0 = n-fastest grid; 1 = m-fastest (W reuse in L2/L3).
// Pure-store paths (!res) use an LDS-staged coalesced epilogue:
//  - fp32 C (logits): nontemporal f32x4 stores (skip cache allocation ->
//    no allocate-fetch; output is never re-read).
//  - bf16 Cb (MLP mid): cached uint4 stores (re-read by next GEMM).
__global__ __launch_bounds__(256) void mfma_gemm_k(const float* __restrict__ A,
                                                   const ushort* __restrict__ Abf,
                                                   const float* __restrict__ W,
                                                   const ushort* __restrict__ Wbf,
                                                   float* __restrict__ C,
                                                   ushort* __restrict__ Cb,
                                                   int M, int N, int K, int ldC,
                                                   int act, int res, int swapg) {
  __shared__ ushort As[128 * 40];
  __shared__ ushort Ws[128 * 40];
  int bm, bn;
  if (swapg == 1) {
    bm = blockIdx.x * 128; bn = blockIdx.y * 128;
  } else {
    bm = blockIdx.y * 128; bn = blockIdx.x * 128;
  }
  const int tid = threadIdx.x;
  const int wave = tid >> 6, lane = tid & 63;
  const int wr = wave >> 1, wc = wave & 1;
  const int lr = lane & 15, lk = (lane >> 4) * 8;   // frag row-in-tile, k-base

  const int srow = tid >> 3;        // 0..31 (fp32 staging, 4 passes)
  const int scol = (tid & 7) * 4;   // 0..28
  const int grow = lane >> 2;       // 0..15 within wave's 16-row slab
  const int gcol = (lane & 3) * 8;  // ushort col 0,8,16,24

  const int PA = Abf ? 32 : 40;
  const int PW = Wbf ? 32 : 40;

  f32x4 acc[4][4] = {};

  for (int k0 = 0; k0 < K; k0 += 32) {
    if (Abf) {
#pragma unroll
      for (int p = 0; p < 2; ++p) {
        int rbase = p * 64 + wave * 16;
        gl_lds16(Abf + (size_t)(bm + rbase + grow) * K + k0 + gcol,
                 &As[rbase * 32]);
      }
    } else {
#pragma unroll
      for (int p = 0; p < 4; ++p) {
        int row = p * 32 + srow;
        float4 av = *reinterpret_cast<const float4*>(A + (size_t)(bm + row) * K + k0 + scol);
        uint2 aw; aw.x = pack2(av.x, av.y); aw.y = pack2(av.z, av.w);
        *reinterpret_cast<uint2*>(&As[row * 40 + scol]) = aw;
      }
    }
    if (Wbf) {
#pragma unroll
      for (int p = 0; p < 2; ++p) {
        int rbase = p * 64 + wave * 16;
        gl_lds16(Wbf + (size_t)(bn + rbase + grow) * K + k0 + gcol,
                 &Ws[rbase * 32]);
      }
    } else {
#pragma unroll
      for (int p = 0; p < 4; ++p) {
        int row = p * 32 + srow;
        float4 wv = *reinterpret_cast<const float4*>(W + (size_t)(bn + row) * K + k0 + scol);
        uint2 ww; ww.x = pack2(wv.x, wv.y); ww.y = pack2(wv.z, wv.w);
        *reinterpret_cast<uint2*>(&Ws[row * 40 + scol]) = ww;
      }
    }
    __syncthreads();
    short8v av[4], bv[4];
#pragma unroll
    for (int m = 0; m < 4; ++m)
      av[m] = *reinterpret_cast<const short8v*>(&As[(wr * 64 + m * 16 + lr) * PA + lk]);
#pragma unroll
    for (int n = 0; n < 4; ++n)
      bv[n] = *reinterpret_cast<const short8v*>(&Ws[(wc * 64 + n * 16 + lr) * PW + lk]);
#pragma unroll
    for (int m = 0; m < 4; ++m)
#pragma unroll
      for (int n = 0; n < 4; ++n)
        acc[m][n] = __builtin_amdgcn_mfma_f32_16x16x32_bf16(av[m], bv[n], acc[m][n], 0, 0, 0);
    __syncthreads();
  }

  const int rj = (lane >> 4) * 4;

  if (!res) {
    // staged epilogue: As is dead after the k-loop; reuse as 16x128 fp32 tile
    float* Cs = (float*)As;           // 8192 B <= 10240 B
    const int rl = tid >> 5;          // 0..7  (fp32 path: 8 rows/sweep)
    const int cf = (tid & 31) * 4;    // 0..124
    const int rl16 = tid >> 4;        // 0..15 (bf16 path: 16 rows/sweep)
    const int cu = (tid & 15) * 8;    // 0..120
#pragma unroll
    for (int p = 0; p < 8; ++p) {
      __syncthreads();
      if (wr == (p >> 2)) {
        const int m = p & 3;
#pragma unroll
        for (int n = 0; n < 4; ++n)
#pragma unroll
          for (int j = 0; j < 4; ++j) {
            float v = acc[m][n][j];
            if (act == ACT_RELU2) { v = fmaxf(v, 0.f); v = v * v; }
            else if (act == ACT_SILU) { v = v / (1.f + expf(-v)); }
            Cs[(rj + j) * 128 + wc * 64 + n * 16 + lr] = v;
          }
      }
      __syncthreads();
      if (Cb) {
        const float* s = &Cs[rl16 * 128 + cu];
        uint4 o;
        o.x = pack2(s[0], s[1]); o.y = pack2(s[2], s[3]);
        o.z = pack2(s[4], s[5]); o.w = pack2(s[6], s[7]);
        *reinterpret_cast<uint4*>(&Cb[(size_t)(bm + p * 16 + rl16) * ldC + bn + cu]) = o;
      } else {
#pragma unroll
        for (int rr = 0; rr < 2; ++rr) {
          int row_l = rr * 8 + rl;                 // 0..15
          f32x4 vv = *reinterpret_cast<const f32x4*>(&Cs[row_l * 128 + cf]);
          __builtin_nontemporal_store(vv, reinterpret_cast<f32x4*>(
              &C[(size_t)(bm + p * 16 + row_l) * ldC + bn + cf]));
        }
      }
    }
    return;
  }

#pragma unroll
  for (int m = 0; m < 4; ++m) {
    int rowb = bm + wr * 64 + m * 16 + rj;
#pragma unroll
    for (int n = 0; n < 4; ++n) {
      int col = bn + wc * 64 + n * 16 + lr;
#pragma unroll
      for (int j = 0; j < 4; ++j) {
        float v = acc[m][n][j];
        if (act == ACT_RELU2) { v = fmaxf(v, 0.f); v = v * v; }
        else if (act == ACT_SILU) { v = v / (1.f + expf(-v)); }
        float* cp = C + (size_t)(rowb + j) * ldC + col;
        v += *cp;
        *cp = v;
      }
    }
  }
}

// ---------------------------------------------------------------- merged QKV(+G) GEMM (bf16 A and W via gl_lds)
// Staged coalesced epilogue (fp32, cached — outputs are re-read downstream).
__global__ __launch_bounds__(256) void qkv_gemm_k(const ushort* __restrict__ Abf,
                                                  const ushort* __restrict__ W0,
                                                  const ushort* __restrict__ W1,
                                                  const ushort* __restrict__ W2,
                                                  const ushort* __restrict__ W3,
                                                  int p0, int p1, int p2,
                                                  float* __restrict__ C0,
                                                  float* __restrict__ C1,
                                                  float* __restrict__ C2,
                                                  float* __restrict__ C3,
                                                  int ldC0, int ldC1, int ldC2, int ldC3,
                                                  int cb0, int cb1, int cb2, int cb3,
                                                  int K) {
  __shared__ ushort As[128 * 32];
  __shared__ ushort Ws[128 * 32];
  const int pn = blockIdx.y;
  const ushort* W; float* C; int ldC; int colb; int dosilu = 0;
  if (pn < p0)      { W = W0 + (size_t)pn * 128 * K;        C = C0; ldC = ldC0; colb = cb0 + pn * 128; }
  else if (pn < p1) { W = W1 + (size_t)(pn - p0) * 128 * K; C = C1; ldC = ldC1; colb = cb1 + (pn - p0) * 128; }
  else if (pn < p2) { W = W2 + (size_t)(pn - p1) * 128 * K; C = C2; ldC = ldC2; colb = cb2 + (pn - p1) * 128; }
  else              { W = W3 + (size_t)(pn - p2) * 128 * K; C = C3; ldC = ldC3; colb = cb3 + (pn - p2) * 128; dosilu = 1; }
  const int bm = blockIdx.x * 128;
  const int tid = threadIdx.x;
  const int wave = tid >> 6, lane = tid & 63;
  const int wr = wave >> 1, wc = wave & 1;
  const int lr = lane & 15, lk = (lane >> 4) * 8;
  const int grow = lane >> 2;
  const int gcol = (lane & 3) * 8;

  f32x4 acc[4][4] = {};

  for (int k0 = 0; k0 < K; k0 += 32) {
#pragma unroll
    for (int p = 0; p < 2; ++p) {
      int rbase = p * 64 + wave * 16;
      gl_lds16(Abf + (size_t)(bm + rbase + grow) * K + k0 + gcol,
               &As[rbase * 32]);
      gl_lds16(W + (size_t)(rbase + grow) * K + k0 + gcol,
               &Ws[rbase * 32]);
    }
    __syncthreads();
    short8v av[4], bv[4];
#pragma unroll
    for (int m = 0; m < 4; ++m)
      av[m] = *reinterpret_cast<const short8v*>(&As[(wr * 64 + m * 16 + lr) * 32 + lk]);
#pragma unroll
    for (int n = 0; n < 4; ++n)
      bv[n] = *reinterpret_cast<const short8v*>(&Ws[(wc * 64 + n * 16 + lr) * 32 + lk]);
#pragma unroll
    for (int m = 0; m < 4; ++m)
#pragma unroll
      for (int n = 0; n < 4; ++n)
        acc[m][n] = __builtin_amdgcn_mfma_f32_16x16x32_bf16(av[m], bv[n], acc[m][n], 0, 0, 0);
    __syncthreads();
  }

  const int rj = (lane >> 4) * 4;
  // staged coalesced epilogue (As dead; 16x128 fp32 tile = 8192 B fits exactly)
  float* Cs = (float*)As;
  const int rl = tid >> 5;          // 0..7
  const int cf = (tid & 31) * 4;    // 0..124
#pragma unroll
  for (int p = 0; p < 8; ++p) {
    __syncthreads();
    if (wr == (p >> 2)) {
      const int m = p & 3;
#pragma unroll
      for (int n = 0; n < 4; ++n)
#pragma unroll
        for (int j = 0; j < 4; ++j) {
          float v = acc[m][n][j];
          if (dosilu) v = v / (1.f + expf(-v));
          Cs[(rj + j) * 128 + wc * 64 + n * 16 + lr] = v;
        }
    }
    __syncthreads();
#pragma unroll
    for (int rr = 0; rr < 2; ++rr) {
      int row_l = rr * 8 + rl;
      float4 vv = *reinterpret_cast<const float4*>(&Cs[row_l * 128 + cf]);
      *reinterpret_cast<float4*>(&C[(size_t)(bm + p * 16 + row_l) * ldC + colb + cf]) = vv;
    }
  }
}

// ---------------------------------------------------------------- fused alpha/beta sigmoid projection
__global__ __launch_bounds__(256) void ab_proj_k(const ushort* __restrict__ hb,
                                                 const float* __restrict__ za,
                                                 const float* __restrict__ zb,
                                                 float* __restrict__ alp,
                                                 float* __restrict__ bet) {
  const int tid = threadIdx.x;
  const int wave = tid >> 6, lane = tid & 63;
  const int l15 = lane & 15, lk = (lane >> 4) * 8;
  const int r0 = blockIdx.x * 64 + wave * 16;
  f32x4 accA = {}, accB = {};
  for (int k0 = 0; k0 < 1024; k0 += 32) {
    short8v a = *reinterpret_cast<const short8v*>(hb + (size_t)(r0 + l15) * 1024 + k0 + lk);
    const float* pa = za + l15 * 1024 + k0 + lk;
    const float* pb = zb + l15 * 1024 + k0 + lk;
    float4 xa = *reinterpret_cast<const float4*>(pa);
    float4 ya = *reinterpret_cast<const float4*>(pa + 4);
    float4 xb = *reinterpret_cast<const float4*>(pb);
    float4 yb = *reinterpret_cast<const float4*>(pb + 4);
    union { short8v v; uint u[4]; } ba, bb;
    ba.u[0] = pack2(xa.x, xa.y); ba.u[1] = pack2(xa.z, xa.w);
    ba.u[2] = pack2(ya.x, ya.y); ba.u[3] = pack2(ya.z, ya.w);
    bb.u[0] = pack2(xb.x, xb.y); bb.u[1] = pack2(xb.z, xb.w);
    bb.u[2] = pack2(yb.x, yb.y); bb.u[3] = pack2(yb.z, yb.w);
    accA = __builtin_amdgcn_mfma_f32_16x16x32_bf16(a, ba.v, accA, 0, 0, 0);
    accB = __builtin_amdgcn_mfma_f32_16x16x32_bf16(a, bb.v, accB, 0, 0, 0);
  }
  const int rj = (lane >> 4) * 4;
#pragma unroll
  for (int j = 0; j < 4; ++j) {
    int row = r0 + rj + j;
    alp[(size_t)row * 16 + l15] = 1.f / (1.f + expf(-accA[j]));
    bet[(size_t)row * 16 + l15] = 1.f / (1.f + expf(-accB[j]));
  }
}

// ---------------------------------------------------------------- l2norm (+gain) (+rope) on rows of 64
__global__ __launch_bounds__(256) void l2n_rope_k(float* __restrict__ P, int NH,
                                                  const float* __restrict__ gain,
                                                  const float* __restrict__ cosT,
                                                  const float* __restrict__ sinT,
                                                  int do_rope) {
  int row = blockIdx.x * 4 + (threadIdx.x >> 6);
  int lane = threadIdx.x & 63;
  size_t idx = (size_t)row * 64 + lane;
  float val = P[idx];
  float ss = val * val;
#pragma unroll
  for (int m = 1; m < 64; m <<= 1) ss += __shfl_xor(ss, m, 64);
  val = val / fmaxf(sqrtf(ss), 1e-6f);
  int hh = row % NH;
  int t = (row / NH) & (TT - 1);
  if (gain) val *= gain[hh];
  if (do_rope) {
    float pr = __shfl_xor(val, 32, 64);
    int jj = lane & 31;
    float c = cosT[t * 32 + jj];
    float s = sinT[t * 32 + jj];
    val = (lane < 32) ? (val * c + pr * s) : (val * c - pr * s);
  }
  P[idx] = val;
}

// ---------------------------------------------------------------- MFMA flash attention (bf16 pre-converted K/V; bf16 out)
__global__ __launch_bounds__(256) void attn_mfma_k(const float* __restrict__ Q,
                                                   const ushort* __restrict__ Kbb,
                                                   const ushort* __restrict__ Vtb,
                                                   ushort* __restrict__ Ob16) {
  __shared__ ushort Ks[64 * 72];
  __shared__ ushort Vt[64 * 72];
  __shared__ ushort Ps[4][16 * 72];

  const int q0 = blockIdx.x * 64;
  const int bh = blockIdx.y;
  const int b = bh >> 4, hh = bh & 15;
  const int kvh = hh >> 2;
  const int tid = threadIdx.x;
  const int wave = tid >> 6, lane = tid & 63;
  const int l15 = lane & 15, l16 = lane >> 4;   // 0..15 / 0..3
  const int rj = l16 * 4;

  const int qrs = HH * 64;    // 1024
  const int krs = KVH * 64;   // 256
  const float* Qb = Q + (size_t)b * TT * qrs + hh * 64;
  const ushort* Kb = Kbb + (size_t)b * TT * krs + kvh * 64;
  const ushort* Vb = Vtb + (size_t)(b * KVH + kvh) * 64 * TT;
  ushort* Ob = Ob16 + (size_t)b * TT * qrs + hh * 64;

  short8v qa[2];
  {
    const float* qp = Qb + (size_t)(q0 + wave * 16 + l15) * qrs + l16 * 8;
#pragma unroll
    for (int dblk = 0; dblk < 2; ++dblk) {
      float4 x = *reinterpret_cast<const float4*>(qp + dblk * 32);
      float4 y = *reinterpret_cast<const float4*>(qp + dblk * 32 + 4);
      union { short8v v; uint u[4]; } tmp;
      tmp.u[0] = pack2(x.x, x.y); tmp.u[1] = pack2(x.z, x.w);
      tmp.u[2] = pack2(y.x, y.y); tmp.u[3] = pack2(y.z, y.w);
      qa[dblk] = tmp.v;
    }
  }

  short8v ones;
  { union { short8v v; uint u[4]; } t;
    t.u[0] = t.u[1] = t.u[2] = t.u[3] = 0x3F803F80u; ones = t.v; }

  f32x4 o[4] = {};
  f32x4 denom = {};

  const int srow = tid >> 2;          // 0..63 (key for Ks, d for Vt)
  const int sc16 = (tid & 3) * 16;    // 16-ushort column base

  for (int kc = 0; kc <= q0; kc += 64) {
    __syncthreads();
    {
      const ushort* kp = Kb + (size_t)(kc + srow) * krs + sc16;
      *reinterpret_cast<short8v*>(&Ks[srow * 72 + sc16]) =
          *reinterpret_cast<const short8v*>(kp);
      *reinterpret_cast<short8v*>(&Ks[srow * 72 + sc16 + 8]) =
          *reinterpret_cast<const short8v*>(kp + 8);
      const ushort* vp = Vb + (size_t)srow * TT + kc + sc16;
      *reinterpret_cast<short8v*>(&Vt[srow * 72 + sc16]) =
          *reinterpret_cast<const short8v*>(vp);
      *reinterpret_cast<short8v*>(&Vt[srow * 72 + sc16 + 8]) =
          *reinterpret_cast<const short8v*>(vp + 8);
    }
    __syncthreads();

    // S = Q @ K^T (16q x 64k)
    f32x4 s[4];
#pragma unroll
    for (int kb = 0; kb < 4; ++kb) {
      short8v k0 = *reinterpret_cast<const short8v*>(&Ks[(kb * 16 + l15) * 72 + l16 * 8]);
      short8v k1 = *reinterpret_cast<const short8v*>(&Ks[(kb * 16 + l15) * 72 + 32 + l16 * 8]);
      f32x4 z = {};
      z = __builtin_amdgcn_mfma_f32_16x16x32_bf16(qa[0], k0, z, 0, 0, 0);
      s[kb] = __builtin_amdgcn_mfma_f32_16x16x32_bf16(qa[1], k1, z, 0, 0, 0);
    }

    // causal mask + exp -> Ps bf16
    const int qg = q0 + wave * 16 + rj;
#pragma unroll
    for (int kb = 0; kb < 4; ++kb) {
      int key = kc + kb * 16 + l15;
#pragma unroll
      for (int j = 0; j < 4; ++j) {
        float p = (key <= qg + j) ? __expf(s[kb][j]) : 0.f;
        Ps[wave][(rj + j) * 72 + kb * 16 + l15] = f2bf(p);
      }
    }

    short8v pa0 = *reinterpret_cast<const short8v*>(&Ps[wave][l15 * 72 + l16 * 8]);
    short8v pa1 = *reinterpret_cast<const short8v*>(&Ps[wave][l15 * 72 + 32 + l16 * 8]);

    f32x4 dz = {};
    dz = __builtin_amdgcn_mfma_f32_16x16x32_bf16(pa0, ones, dz, 0, 0, 0);
    dz = __builtin_amdgcn_mfma_f32_16x16x32_bf16(pa1, ones, dz, 0, 0, 0);
    denom += dz;

#pragma unroll
    for (int db = 0; db < 4; ++db) {
      short8v v0 = *reinterpret_cast<const short8v*>(&Vt[(db * 16 + l15) * 72 + l16 * 8]);
      short8v v1 = *reinterpret_cast<const short8v*>(&Vt[(db * 16 + l15) * 72 + 32 + l16 * 8]);
      o[db] = __builtin_amdgcn_mfma_f32_16x16x32_bf16(pa0, v0, o[db], 0, 0, 0);
      o[db] = __builtin_amdgcn_mfma_f32_16x16x32_bf16(pa1, v1, o[db], 0, 0, 0);
    }
  }

  const int qg = q0 + wave * 16 + rj;
#pragma unroll
  for (int j = 0; j < 4; ++j) {
    float inv = 1.0f / denom[j];
    ushort* op = Ob + (size_t)(qg + j) * qrs;
#pragma unroll
    for (int db = 0; db < 4; ++db) op[db * 16 + l15] = f2bf(o[db][j] * inv);
  }
}

// ---------------------------------------------------------------- causal depthwise conv (CK=4) + silu + split
__global__ __launch_bounds__(256) void conv_k(const float* __restrict__ X,
                                              const float* __restrict__ Wc,
                                              float* __restrict__ Qo,
                                              float* __restrict__ Ko,
                                              float* __restrict__ Vo) {
  int idx = blockIdx.x * 256 + threadIdx.x;   // B*T*3072 exact
  int c = idx % 3072;
  int rest = idx / 3072;
  int t = rest & (TT - 1);
  int b = rest >> 10;
  const float* w = Wc + c * 4;
  float acc = 0.f;
#pragma unroll
  for (int j = 0; j < 4; ++j) {
    int tt = t - 3 + j;
    if (tt >= 0) acc += w[j] * X[((size_t)(b * TT + tt)) * 3072 + c];
  }
  float y = acc / (1.f + expf(-acc));   // silu
  int which = c >> 10, cc = c & 1023;
  float* dst = (which == 0) ? Qo : ((which == 1) ? Ko : Vo);
  dst[((size_t)(b * TT + t)) * 1024 + cc] = y;
}

// ---------------------------------------------------------------- GDN segmented scan
__global__ __launch_bounds__(256) void gdn_p1_k(const float* __restrict__ Kg,
                                                const float* __restrict__ Vg,
                                                const float* __restrict__ Al,
                                                const float* __restrict__ Be,
                                                float* __restrict__ Aseg,
                                                float* __restrict__ Useg) {
  __shared__ float Kl[2][CH * 64];
  __shared__ float Vl[2][CH * 64];
  __shared__ float As_[2][CH];
  __shared__ float Bs_[2][CH];

  const int seg = blockIdx.x;            // 0..7
  const int bh = blockIdx.y;             // 0..31
  const int basis = (blockIdx.z == 0);
  const int b = bh >> 4, hh = bh & 15;
  const int tid = threadIdx.x;
  const int wave = tid >> 6;
  const int lane = tid & 63;
  const int vloc = lane >> 2;
  const int dgrp = lane & 3;
  const int d0 = dgrp * 16;
  const int v = wave * 16 + vloc;

  const size_t base = (size_t)b * TT * 1024 + hh * 64 + (size_t)seg * SEGL * 1024;
  const size_t ab0 = (size_t)b * TT * HH + hh + (size_t)seg * SEGL * HH;

  const int s_step = tid >> 4;
  const int s_col = (tid & 15) * 4;

  float S[16];
#pragma unroll
  for (int i = 0; i < 16; ++i) S[i] = (basis && (d0 + i == v)) ? 1.f : 0.f;

  float4 kst[2], vst[2];
  float ast = 0.f, bst = 0.f;

#define ISSUE(c0)                                                              \
  {                                                                            \
    _Pragma("unroll") for (int p = 0; p < 2; ++p) {                            \
      int st = p * 16 + s_step;                                                \
      size_t off = base + (size_t)((c0) + st) * 1024 + s_col;                  \
      kst[p] = *reinterpret_cast<const float4*>(Kg + off);                     \
      if (!basis) vst[p] = *reinterpret_cast<const float4*>(Vg + off);         \
    }                                                                          \
    if (tid < CH) ast = Al[ab0 + (size_t)((c0) + tid) * HH];                   \
    else if (tid < 2 * CH) bst = Be[ab0 + (size_t)((c0) + tid - CH) * HH];     \
  }

#define WRITE(ib)                                                              \
  {                                                                            \
    _Pragma("unroll") for (int p = 0; p < 2; ++p) {                            \
      int st = p * 16 + s_step;                                                \
      *reinterpret_cast<float4*>(&Kl[ib][st * 64 + s_col]) = kst[p];           \
      if (!basis) *reinterpret_cast<float4*>(&Vl[ib][st * 64 + s_col]) = vst[p];\
    }                                                                          \
    if (tid < CH) As_[ib][tid] = ast;                                          \
    else if (tid < 2 * CH) Bs_[ib][tid - CH] = bst;                            \
  }

#define LOADL(KX, VX, AX, BX, ib, tt)                                          \
  {                                                                            \
    const float* kp = &Kl[ib][(tt) * 64 + d0];                                 \
    _Pragma("unroll") for (int i = 0; i < 4; ++i) {                            \
      float4 kv = *reinterpret_cast<const float4*>(kp + i * 4);                \
      KX[4 * i] = kv.x; KX[4 * i + 1] = kv.y;                                  \
      KX[4 * i + 2] = kv.z; KX[4 * i + 3] = kv.w;                              \
    }                                                                          \
    VX = basis ? 0.f : Vl[ib][(tt) * 64 + v];                                  \
    AX = As_[ib][(tt)];                                                        \
    BX = Bs_[ib][(tt)];                                                        \
  }

#define STEP(KX, VX, AX, BX)                                                   \
  {                                                                            \
    float t0 = 0.f, t1 = 0.f, t2 = 0.f, t3 = 0.f;                              \
    _Pragma("unroll") for (int i = 0; i < 16; i += 4) {                        \
      t0 += KX[i] * S[i];                                                      \
      t1 += KX[i + 1] * S[i + 1];                                              \
      t2 += KX[i + 2] * S[i + 2];                                              \
      t3 += KX[i + 3] * S[i + 3];                                              \
    }                                                                          \
    float ks = qadd4((t0 + t1) + (t2 + t3));                                   \
    float cin = VX - AX * BX * ks;                                             \
    _Pragma("unroll") for (int i = 0; i < 16; ++i)                             \
      S[i] = AX * S[i] + cin * KX[i];                                          \
  }

  float kA[16], kB[16];
  float vA, aA, btA, vB, aB, btB;

  const int NC = SEGL / CH;   // 4 chunks
  ISSUE(0);
  WRITE(0);
  __syncthreads();
  ISSUE(CH);
  for (int cnk = 0; cnk < NC; ++cnk) {
    const int ib = cnk & 1;
    LOADL(kA, vA, aA, btA, ib, 0);
    for (int t = 0; t < CH; t += 2) {
      LOADL(kB, vB, aB, btB, ib, t + 1);
      STEP(kA, vA, aA, btA);
      if (t + 2 < CH) LOADL(kA, vA, aA, btA, ib, t + 2);
      STEP(kB, vB, aB, btB);
    }
    if (cnk + 1 < NC) {
      WRITE(ib ^ 1);
      __syncthreads();
      if (cnk + 2 < NC) ISSUE((cnk + 2) * CH);
    }
  }
#undef ISSUE
#undef WRITE
#undef LOADL
#undef STEP

  float* dst = (basis ? Aseg : Useg) + (size_t)(bh * 8 + seg) * 4096;
#pragma unroll
  for (int i = 0; i < 16; ++i) dst[(d0 + i) * 64 + v] = S[i];
}

__global__ __launch_bounds__(256) void gdn_p2_k(const float* __restrict__ Aseg,
                                                const float* __restrict__ Useg,
                                                float* __restrict__ S0) {
  __shared__ float Sc[4096];
  const int bh = blockIdx.x;
  const int tid = threadIdx.x;
  for (int i = tid; i < 4096; i += 256) Sc[i] = 0.f;
  __syncthreads();
  const int dr = tid >> 2;         // 0..63 (row)
  const int v4 = (tid & 3) * 16;   // col base
  for (int s = 0; s < 8; ++s) {
    for (int i = tid; i < 4096; i += 256) S0[(size_t)(bh * 8 + s) * 4096 + i] = Sc[i];
    if (s == 7) break;
    const float* Arow = Aseg + (size_t)(bh * 8 + s) * 4096 + dr * 64;
    const float* Up = Useg + (size_t)(bh * 8 + s) * 4096 + dr * 64 + v4;
    float acc[16];
#pragma unroll
    for (int i = 0; i < 16; ++i) acc[i] = Up[i];
    for (int j = 0; j < 64; ++j) {
      float a = Arow[j];
      const float* sr = &Sc[j * 64 + v4];
#pragma unroll
      for (int i = 0; i < 16; ++i) acc[i] += a * sr[i];
    }
    __syncthreads();
#pragma unroll
    for (int i = 0; i < 16; ++i) Sc[dr * 64 + v4 + i] = acc[i];
    __syncthreads();
  }
}

__global__ __launch_bounds__(256) void gdn_p3_k(const float* __restrict__ Qg,
                                                const float* __restrict__ Kg,
                                                const float* __restrict__ Vg,
                                                const float* __restrict__ Al,
                                                const float* __restrict__ Be,
                                                const float* __restrict__ S0,
                                                float* __restrict__ Og) {
  __shared__ float Kl[2][CH * 64];
  __shared__ float Ql[2][CH * 64];
  __shared__ float Vl[2][CH * 64];
  __shared__ float As_[2][CH];
  __shared__ float Bs_[2][CH];

  const int seg = blockIdx.x;            // 0..7
  const int bh = blockIdx.y;             // 0..31
  const int b = bh >> 4, hh = bh & 15;
  const int tid = threadIdx.x;
  const int wave = tid >> 6;
  const int lane = tid & 63;
  const int vloc = lane >> 2;
  const int dgrp = lane & 3;
  const int d0 = dgrp * 16;
  const int v = wave * 16 + vloc;

  const size_t base = (size_t)b * TT * 1024 + hh * 64 + (size_t)seg * SEGL * 1024;
  const size_t ab0 = (size_t)b * TT * HH + hh + (size_t)seg * SEGL * HH;

  const int s_step = tid >> 4;
  const int s_col = (tid & 15) * 4;

  float S[16];
  {
    const float* sp = S0 + (size_t)(bh * 8 + seg) * 4096;
#pragma unroll
    for (int i = 0; i < 16; ++i) S[i] = sp[(d0 + i) * 64 + v];
  }

  float4 kst[2], qst[2], vst[2];
  float ast = 0.f, bst = 0.f;

#define ISSUE(c0)                                                              \
  {                                                                            \
    _Pragma("unroll") for (int p = 0; p < 2; ++p) {                            \
      int st = p * 16 + s_step;                                                \
      size_t off = base + (size_t)((c0) + st) * 1024 + s_col;                  \
      kst[p] = *reinterpret_cast<const float4*>(Kg + off);                     \
      qst[p] = *reinterpret_cast<const float4*>(Qg + off);                     \
      vst[p] = *reinterpret_cast<const float4*>(Vg + off);                     \
    }                                                                          \
    if (tid < CH) ast = Al[ab0 + (size_t)((c0) + tid) * HH];                   \
    else if (tid < 2 * CH) bst = Be[ab0 + (size_t)((c0) + tid - CH) * HH];     \
  }

#define WRITE(ib)                                                              \
  {                                                                            \
    _Pragma("unroll") for (int p = 0; p < 2; ++p) {                            \
      int st = p * 16 + s_step;                                                \
      *reinterpret_cast<float4*>(&Kl[ib][st * 64 + s_col]) = kst[p];           \
      *reinterpret_cast<float4*>(&Ql[ib][st * 64 + s_col]) = qst[p];           \
      *reinterpret_cast<float4*>(&Vl[ib][st * 64 + s_col]) = vst[p];           \
    }                                                                          \
    if (tid < CH) As_[ib][tid] = ast;                                          \
    else if (tid < 2 * CH) Bs_[ib][tid - CH] = bst;                            \
  }

#define LOADL(KX, QX, VX, AX, BX, ib, tt)                                      \
  {                                                                            \
    const float* kp = &Kl[ib][(tt) * 64 + d0];                                 \
    const float* qp = &Ql[ib][(tt) * 64 + d0];                                 \
    _Pragma("unroll") for (int i = 0; i < 4; ++i) {                            \
      float4 kv = *reinterpret_cast<const float4*>(kp + i * 4);                \
      KX[4 * i] = kv.x; KX[4 * i + 1] = kv.y;                                  \
      KX[4 * i + 2] = kv.z; KX[4 * i + 3] = kv.w;                              \
      float4 qv = *reinterpret_cast<const float4*>(qp + i * 4);                \
      QX[4 * i] = qv.x; QX[4 * i + 1] = qv.y;                                  \
      QX[4 * i + 2] = qv.z; QX[4 * i + 3] = qv.w;                              \
    }                                                                          \
    VX = Vl[ib][(tt) * 64 + v];                                                \
    AX = As_[ib][(tt)];                                                        \
    BX = Bs_[ib][(tt)];                                                        \
  }

#define STEP(KX, QX, VX, AX, BX, gt)                                           \
  {                                                                            \
    float t0 = 0.f, t1 = 0.f, t2 = 0.f, t3 = 0.f;                              \
    _Pragma("unroll") for (int i = 0; i < 16; i += 4) {                        \
      t0 += KX[i] * S[i];                                                      \
      t1 += KX[i + 1] * S[i + 1];                                              \
      t2 += KX[i + 2] * S[i + 2];                                              \
      t3 += KX[i + 3] * S[i + 3];                                              \
    }                                                                          \
    float ks = qadd4((t0 + t1) + (t2 + t3));                                   \
    float cin = VX - AX * BX * ks;                                             \
    float o0 = 0.f, o1 = 0.f, o2 = 0.f, o3 = 0.f;                              \
    _Pragma("unroll") for (int i = 0; i < 16; i += 4) {                        \
      S[i] = AX * S[i] + cin * KX[i];               o0 += QX[i] * S[i];        \
      S[i + 1] = AX * S[i + 1] + cin * KX[i + 1];   o1 += QX[i + 1] * S[i + 1];\
      S[i + 2] = AX * S[i + 2] + cin * KX[i + 2];   o2 += QX[i + 2] * S[i + 2];\
      S[i + 3] = AX * S[i + 3] + cin * KX[i + 3];   o3 += QX[i + 3] * S[i + 3];\
    }                                                                          \
    float o = qadd4((o0 + o1) + (o2 + o3));                                    \
    if (dgrp == 0) Og[base + (size_t)(gt) * 1024 + v] = o;                     \
  }

  float kA[16], qA[16], kB[16], qB[16];
  float vA, aA, btA, vB, aB, btB;

  const int NC = SEGL / CH;   // 4 chunks
  ISSUE(0);
  WRITE(0);
  __syncthreads();
  ISSUE(CH);
  for (int cnk = 0; cnk < NC; ++cnk) {
    const int ib = cnk & 1;
    LOADL(kA, qA, vA, aA, btA, ib, 0);
    for (int t = 0; t < CH; t += 2) {
      LOADL(kB, qB, vB, aB, btB, ib, t + 1);
      STEP(kA, qA, vA, aA, btA, cnk * CH + t);
      if (t + 2 < CH) LOADL(kA, qA, vA, aA, btA, ib, t + 2);
      STEP(kB, qB, vB, aB, btB, cnk * CH + t + 1);
    }
    if (cnk + 1 < NC) {
      WRITE(ib ^ 1);
      __syncthreads();
      if (cnk + 2 < NC) ISSUE((cnk + 2) * CH);
    }
  }
#undef ISSUE
#undef WRITE
#undef LOADL
#undef STEP
}

// ---------------------------------------------------------------- rmsnorm over 64 * gate -> bf16 out
__global__ __launch_bounds__(256) void rms64_mul_k(const float* __restrict__ O,
                                                   const float* __restrict__ G,
                                                   ushort* __restrict__ Ob) {
  int row = blockIdx.x * 4 + (threadIdx.x >> 6);
  int lane = threadIdx.x & 63;
  size_t idx = (size_t)row * 64 + lane;
  float val = O[idx];
  float ss = val * val;
#pragma unroll
  for (int m = 1; m < 64; m <<= 1) ss += __shfl_xor(ss, m, 64);
  float sc = rsqrtf(ss * (1.0f / 64.0f) + 1e-6f);
  Ob[idx] = f2bf(val * sc * G[idx]);
}

// ---------------------------------------------------------------- host-side launch
static inline void gemm(hipStream_t s, const float* A, const ushort* Abf,
                        const float* W, const ushort* Wbf, float* C, ushort* Cb,
                        int M, int N, int K, int ldC, int act, int res) {
  int swap = (N >= 2048) ? 1 : 0;
  dim3 g = swap ? dim3(M / 128, N / 128) : dim3(N / 128, M / 128);
  mfma_gemm_k<<<g, 256, 0, s>>>(A, Abf, W, Wbf, C, Cb, M, N, K, ldC, act, res, swap);
}

extern "C" void kernel_launch(void* const* d_in, const int* in_sizes, int n_in,
                              void* d_out, int out_size, void* d_ws, size_t ws_size,
                              hipStream_t stream) {
  const int*   tokens = (const int*)d_in[0];
  const float* emb    = (const float*)d_in[1];
  const float* aw_q   = (const float*)d_in[2];
  const float* aw_k   = (const float*)d_in[3];
  const float* aw_v   = (const float*)d_in[4];
  const float* aw_o   = (const float*)d_in[5];
  const float* a_gain = (const float*)d_in[6];
  const float* a_m1   = (const float*)d_in[7];
  const float* a_m2   = (const float*)d_in[8];
  const float* g_wq   = (const float*)d_in[9];
  const float* g_wk   = (const float*)d_in[10];
  const float* g_wv   = (const float*)d_in[11];
  const float* g_wa   = (const float*)d_in[12];
  const float* g_wb   = (const float*)d_in[13];
  const float* g_wg   = (const float*)d_in[14];
  const float* g_wo   = (const float*)d_in[15];
  const float* g_conv = (const float*)d_in[16];
  const float* g_m1   = (const float*)d_in[17];
  const float* g_m2   = (const float*)d_in[18];

  const int M = BB * TT;  // 2048

  // ---- d_out scratch (fully rewritten by the final logits GEMM; nothing here read during it)
  float* outF = (float*)d_out;
  ushort* midb = (ushort*)outF;              // [0, 4194304) floats as bf16 M*DFF
  float* scanA = outF + 4194304;             // 1048576 (gdn A_seg)
  float* scanU = scanA + 1048576;            // 1048576 (gdn U_seg)
  float* scanS = scanU + 1048576;            // 1048576 (gdn S0)
  ushort* kbb = (ushort*)(outF + 7340032);   // 524288 ushorts (bf16 attn K)
  ushort* vtb = kbb + 524288;                // 524288 ushorts (bf16 attn V^T)
  float* qkv  = outF + 8388608;              // [8388608, 14680064)  B*T*3072
  ushort* hb  = (ushort*)(outF + 14680064);  // [14680064, 15728640) bf16 h

  // bf16 weight cache [15728640, 40370176)
  ushort* wtb = (ushort*)(outF + 15728640);
  ushort* awq_b = wtb;                 // 2097152 (both layers)
  ushort* awk_b = awq_b + 2097152;     // 524288
  ushort* awv_b = awk_b + 524288;      // 524288
  ushort* awo_b = awv_b + 524288;      // 2097152
  ushort* am1_b = awo_b + 2097152;     // 8388608
  ushort* am2_b = am1_b + 8388608;     // 8388608
  ushort* gwq_b = am2_b + 8388608;     // 2097152
  ushort* gwk_b = gwq_b + 2097152;     // 2097152
  ushort* gwv_b = gwk_b + 2097152;     // 2097152
  ushort* gwg_b = gwv_b + 2097152;     // 2097152
  ushort* gwo_b = gwg_b + 2097152;     // 2097152
  ushort* gm1_b = gwo_b + 2097152;     // 8388608
  ushort* gm2_b = gm1_b + 8388608;     // 8388608  (ends at float 40370176)

  // per-layer activations [40370176, ...); qgb/ogb are M*1024 = 2097152 ushorts each
  float* qb   = outF + 40370176;             // 2097152 -> ends 42467328
  float* kb   = qb + 2097152;                // 524288  -> ends 42991616
  float* vb   = kb + 524288;                 // 524288  -> ends 43515904
  float* qg   = vb + 524288;                 // 2097152 -> ends 45613056
  float* kg   = qg + 2097152;                // 2097152 -> ends 47710208
  float* vg   = kg + 2097152;                // 2097152 -> ends 49807360
  float* og   = vg + 2097152;                // 2097152 -> ends 51904512
  float* gb   = og + 2097152;                // 2097152 -> ends 54001664
  ushort* qgb = (ushort*)(gb + 2097152);     // 2097152 ushorts -> float [54001664, 55050240)
  ushort* ogb = qgb + 2097152;               // 2097152 ushorts -> float [55050240, 56098816)
  float* x    = outF + 56098816;             // 2097152 -> ends 58195968
  float* alp  = outF + 58195968;             // 32768
  float* bet  = alp + 32768;                 // 32768
  float* cosT = bet + 32768;                 // 32768
  float* sinT = cosT + 32768;                // 32768 -> ends 58327040
  float* h    = outF + 58327040;             // 2097152 -> ends 60424192 (< 67108864)

  // ---- ws: {embb, hbL} = 71,303,168 B (within the 71,827,456 B footprint
  // proven safe by rounds 1-19).
  ushort* embb = (ushort*)d_ws;                 // VV*DD ushorts (64 MiB)
  ushort* hbL  = embb + (size_t)VV * DD;        // M*DD ushorts (4 MB)

  rope_tab_k<<<128, 256, 0, stream>>>(cosT, sinT);
  embed_k<<<M, 256, 0, stream>>>(tokens, emb, x);
  cvt_bf_k<<<2048, 256, 0, stream>>>(emb, embb, (VV * DD) / 8);

  // pre-convert all layer weights to bf16 (one-time per launch)
  cvt_bf_k<<<1024, 256, 0, stream>>>(aw_q, awq_b, 2097152 / 8);
  cvt_bf_k<<<512, 256, 0, stream>>>(aw_k, awk_b, 524288 / 8);
  cvt_bf_k<<<512, 256, 0, stream>>>(aw_v, awv_b, 524288 / 8);
  cvt_bf_k<<<1024, 256, 0, stream>>>(aw_o, awo_b, 2097152 / 8);
  cvt_bf_k<<<2048, 256, 0, stream>>>(a_m1, am1_b, 8388608 / 8);
  cvt_bf_k<<<2048, 256, 0, stream>>>(a_m2, am2_b, 8388608 / 8);
  cvt_bf_k<<<1024, 256, 0, stream>>>(g_wq, gwq_b, 2097152 / 8);
  cvt_bf_k<<<1024, 256, 0, stream>>>(g_wk, gwk_b, 2097152 / 8);
  cvt_bf_k<<<1024, 256, 0, stream>>>(g_wv, gwv_b, 2097152 / 8);
  cvt_bf_k<<<1024, 256, 0, stream>>>(g_wg, gwg_b, 2097152 / 8);
  cvt_bf_k<<<1024, 256, 0, stream>>>(g_wo, gwo_b, 2097152 / 8);
  cvt_bf_k<<<2048, 256, 0, stream>>>(g_m1, gm1_b, 8388608 / 8);
  cvt_bf_k<<<2048, 256, 0, stream>>>(g_m2, gm2_b, 8388608 / 8);

  for (int i = 0; i < 2; ++i) {
    const float* za = g_wa + (size_t)i * 16 * 1024;
    const float* zb = g_wb + (size_t)i * 16 * 1024;
    const float* zc = g_conv + (size_t)i * 3072 * 4;
    const ushort* wq_b = awq_b + (size_t)i * 1048576;
    const ushort* wk_b = awk_b + (size_t)i * 262144;
    const ushort* wv_b = awv_b + (size_t)i * 262144;
    const ushort* wo_b = awo_b + (size_t)i * 1048576;
    const ushort* m1_b = am1_b + (size_t)i * 4194304;
    const ushort* m2_b = am2_b + (size_t)i * 4194304;
    const ushort* zq_b = gwq_b + (size_t)i * 1048576;
    const ushort* zk_b = gwk_b + (size_t)i * 1048576;
    const ushort* zv_b = gwv_b + (size_t)i * 1048576;
    const ushort* zg_b = gwg_b + (size_t)i * 1048576;
    const ushort* zo_b = gwo_b + (size_t)i * 1048576;
    const ushort* n1_b = gm1_b + (size_t)i * 4194304;
    const ushort* n2_b = gm2_b + (size_t)i * 4194304;

    // ---------------- attention block ----------------
    rmsnorm_k<<<M, 256, 0, stream>>>(x, h, hb);
    qkv_gemm_k<<<dim3(M / 128, 12), 256, 0, stream>>>(
        hb, wq_b, wk_b, wv_b, nullptr, 8, 10, 12,
        qb, kb, vb, nullptr, 1024, 256, 256, 0, 0, 0, 0, 0, 1024);
    l2n_rope_k<<<(M * HH) / 4, 256, 0, stream>>>(qb, HH, a_gain + (size_t)i * 16, cosT, sinT, 1);
    l2n_rope_k<<<(M * KVH) / 4, 256, 0, stream>>>(kb, KVH, nullptr, cosT, sinT, 1);
    cvt_bf_k<<<256, 256, 0, stream>>>(kb, kbb, (M * 256) / 8);
    cvt_vt_k<<<2048, 256, 0, stream>>>(vb, vtb);
    attn_mfma_k<<<dim3(TT / 64, BB * HH), 256, 0, stream>>>(qb, kbb, vtb, qgb);
    gemm(stream, nullptr, qgb, nullptr, wo_b, x, nullptr, M, 1024, 1024, 1024, ACT_NONE, 1);
    rmsnorm_k<<<M, 256, 0, stream>>>(x, h, hb);
    gemm(stream, nullptr, hb, nullptr, m1_b, nullptr, midb, M, DFF, 1024, DFF, ACT_RELU2, 0);
    gemm(stream, nullptr, midb, nullptr, m2_b, x, nullptr, M, 1024, DFF, 1024, ACT_NONE, 1);

    // ---------------- GDN block ----------------
    rmsnorm_k<<<M, 256, 0, stream>>>(x, h, hb);
    qkv_gemm_k<<<dim3(M / 128, 32), 256, 0, stream>>>(
        hb, zq_b, zk_b, zv_b, zg_b, 8, 16, 24,
        qkv, qkv, qkv, gb, 3072, 3072, 3072, 1024, 0, 1024, 2048, 0, 1024);
    conv_k<<<(M * 3072) / 256, 256, 0, stream>>>(qkv, zc, qg, kg, vg);
    l2n_rope_k<<<(M * HH) / 4, 256, 0, stream>>>(qg, HH, nullptr, nullptr, nullptr, 0);
    l2n_rope_k<<<(M * HH) / 4, 256, 0, stream>>>(kg, HH, nullptr, nullptr, nullptr, 0);
    ab_proj_k<<<M / 64, 256, 0, stream>>>(hb, za, zb, alp, bet);
    gdn_p1_k<<<dim3(8, BB * HH, 2), 256, 0, stream>>>(kg, vg, alp, bet, scanA, scanU);
    gdn_p2_k<<<BB * HH, 256, 0, stream>>>(scanA, scanU, scanS);
    gdn_p3_k<<<dim3(8, BB * HH), 256, 0, stream>>>(qg, kg, vg, alp, bet, scanS, og);
    rms64_mul_k<<<(M * HH) / 4, 256, 0, stream>>>(og, gb, ogb);
    gemm(stream, nullptr, ogb, nullptr, zo_b, x, nullptr, M, 1024, 1024, 1024, ACT_NONE, 1);
    rmsnorm_k<<<M, 256, 0, stream>>>(x, h, hb);
    gemm(stream, nullptr, hb, nullptr, n1_b, nullptr, midb, M, DFF, 1024, DFF, ACT_RELU2, 0);
    gemm(stream, nullptr, midb, nullptr, n2_b, x, nullptr, M, 1024, DFF, 1024, ACT_NONE, 1);
  }

  // ---------------- final logits: A = hbL (bf16, ws), W = embb (bf16, ws).
  rmsnorm_k<<<M, 256, 0, stream>>>(x, h, hbL);
  gemm(stream, nullptr, hbL, nullptr, embb, outF, nullptr, M, VV, 1024, VV, ACT_NONE, 0);
}

// Round 29
// 1847.832 us; speedup vs baseline: 1.0838x; 1.0838x over previous
//
#include <hip/hip_runtime.h>
#include <hip/hip_bf16.h>
#include <math.h>

// ---------------------------------------------------------------- constants
#define BB 2
#define TT 1024
#define DD 1024
#define HH 16
#define KVH 4
#define HDIM 64
#define VV 32768
#define DFF 4096
#define CH 32    // gdn scan chunk (steps staged in LDS per buffer)
#define SEGL 128 // gdn segmented-scan segment length (8 segments)

#define ACT_NONE 0
#define ACT_RELU2 1
#define ACT_SILU 2
#define ACT_SIG 3

typedef __attribute__((ext_vector_type(8))) short short8v;
typedef __attribute__((ext_vector_type(4))) float f32x4;

__device__ inline ushort f2bf(float f) {
  uint u = __float_as_uint(f);
  uint r = u + 0x7FFFu + ((u >> 16) & 1u);
  return (ushort)(r >> 16);
}
__device__ inline uint pack2(float lo, float hi) {
  return (uint)f2bf(lo) | ((uint)f2bf(hi) << 16);
}

// 4-lane (quad) sum via DPP quad_perm: xor1 (0xB1) then xor2 (0x4E). VALU-speed.
__device__ inline float qadd4(float x) {
  float y = __int_as_float(__builtin_amdgcn_update_dpp(
      0, __float_as_int(x), 0xB1, 0xF, 0xF, true));
  x += y;
  float z = __int_as_float(__builtin_amdgcn_update_dpp(
      0, __float_as_int(x), 0x4E, 0xF, 0xF, true));
  return x + z;
}

// async global->LDS, 16B/lane: dst = wave-uniform LDS base + lane*16
__device__ inline void gl_lds16(const void* g, void* l) {
  __builtin_amdgcn_global_load_lds(
      (const __attribute__((address_space(1))) void*)g,
      (__attribute__((address_space(3))) void*)l, 16, 0, 0);
}

// ---------------------------------------------------------------- f32 -> bf16 bulk convert
__global__ __launch_bounds__(256) void cvt_bf_k(const float* __restrict__ src,
                                                ushort* __restrict__ dst, int n8) {
  for (int i = blockIdx.x * 256 + threadIdx.x; i < n8; i += gridDim.x * 256) {
    const float4 a = *reinterpret_cast<const float4*>(src + (size_t)i * 8);
    const float4 b = *reinterpret_cast<const float4*>(src + (size_t)i * 8 + 4);
    uint4 o;
    o.x = pack2(a.x, a.y); o.y = pack2(a.z, a.w);
    o.z = pack2(b.x, b.y); o.w = pack2(b.z, b.w);
    *reinterpret_cast<uint4*>(dst + (size_t)i * 8) = o;
  }
}

// ---------------------------------------------------------------- V transpose+convert: vtb[b][kvh][d][t] = bf16(vb[b][t][kvh*64+d])
__global__ __launch_bounds__(256) void cvt_vt_k(const float* __restrict__ vb,
                                                ushort* __restrict__ vtb) {
  int idx = blockIdx.x * 256 + threadIdx.x;   // B*KVH*64*1024 = 524288
  int t = idx & 1023;
  int rest = idx >> 10;
  int d = rest & 63;
  int bk = rest >> 6;        // b*KVH + kvh
  int b = bk >> 2, kvh = bk & 3;
  float v = vb[((size_t)(b * TT + t)) * 256 + kvh * 64 + d];
  vtb[idx] = f2bf(v);
}

// ---------------------------------------------------------------- rope tables
__global__ __launch_bounds__(256) void rope_tab_k(float* __restrict__ cosT,
                                                  float* __restrict__ sinT) {
  int idx = blockIdx.x * 256 + threadIdx.x;   // T*32 = 32768 total
  int t = idx >> 5, j = idx & 31;
  float inv = 1.0f / powf(10000.0f, (float)(2 * j) * (1.0f / 64.0f));
  float fr = (float)t * inv;
  cosT[idx] = cosf(fr);
  sinT[idx] = sinf(fr);
}

// ---------------------------------------------------------------- embedding gather
__global__ __launch_bounds__(256) void embed_k(const int* __restrict__ tok,
                                               const float* __restrict__ emb,
                                               float* __restrict__ X) {
  int row = blockIdx.x;          // B*T rows
  int tid = threadIdx.x;
  int tk = tok[row];
  float4 v = *reinterpret_cast<const float4*>(emb + (size_t)tk * DD + tid * 4);
  *reinterpret_cast<float4*>(X + (size_t)row * DD + tid * 4) = v;
}

// ---------------------------------------------------------------- rmsnorm over D=1024 (+ optional bf16 copy)
__global__ __launch_bounds__(256) void rmsnorm_k(const float* __restrict__ in,
                                                 float* __restrict__ out,
                                                 ushort* __restrict__ outb) {
  int row = blockIdx.x;
  int tid = threadIdx.x;
  const float* p = in + (size_t)row * DD;
  float4 v = *reinterpret_cast<const float4*>(p + tid * 4);
  float ss = v.x * v.x + v.y * v.y + v.z * v.z + v.w * v.w;
#pragma unroll
  for (int m = 1; m < 64; m <<= 1) ss += __shfl_xor(ss, m, 64);
  __shared__ float wsum[4];
  int wid = tid >> 6, lane = tid & 63;
  if (lane == 0) wsum[wid] = ss;
  __syncthreads();
  float tot = wsum[0] + wsum[1] + wsum[2] + wsum[3];
  float sc = rsqrtf(tot * (1.0f / 1024.0f) + 1e-6f);
  float4 o;
  o.x = v.x * sc; o.y = v.y * sc; o.z = v.z * sc; o.w = v.w * sc;
  *reinterpret_cast<float4*>(out + (size_t)row * DD + tid * 4) = o;
  if (outb) {
    uint2 t; t.x = pack2(o.x, o.y); t.y = pack2(o.z, o.w);
    *reinterpret_cast<uint2*>(outb + (size_t)row * DD + tid * 4) = t;
  }
}

// ---------------------------------------------------------------- MFMA bf16 GEMM: C = [res +] act(A @ W^T)
// swapg: 0 = n-fastest grid; 1 = m-fastest (W reuse in L2/L3).
// The plain fp32-C no-res path (logits) stages the C tile through LDS and
// emits fully-coalesced cached float4 rows (verified R26: logits 255->233us).
__global__ __launch_bounds__(256) void mfma_gemm_k(const float* __restrict__ A,
                                                   const ushort* __restrict__ Abf,
                                                   const float* __restrict__ W,
                                                   const ushort* __restrict__ Wbf,
                                                   float* __restrict__ C,
                                                   ushort* __restrict__ Cb,
                                                   int M, int N, int K, int ldC,
                                                   int act, int res, int swapg) {
  __shared__ ushort As[128 * 40];
  __shared__ ushort Ws[128 * 40];
  int bm, bn;
  if (swapg == 1) {
    bm = blockIdx.x * 128; bn = blockIdx.y * 128;
  } else {
    bm = blockIdx.y * 128; bn = blockIdx.x * 128;
  }
  const int tid = threadIdx.x;
  const int wave = tid >> 6, lane = tid & 63;
  const int wr = wave >> 1, wc = wave & 1;
  const int lr = lane & 15, lk = (lane >> 4) * 8;   // frag row-in-tile, k-base

  const int srow = tid >> 3;        // 0..31 (fp32 staging, 4 passes)
  const int scol = (tid & 7) * 4;   // 0..28
  const int grow = lane >> 2;       // 0..15 within wave's 16-row slab
  const int gcol = (lane & 3) * 8;  // ushort col 0,8,16,24

  const int PA = Abf ? 32 : 40;
  const int PW = Wbf ? 32 : 40;

  f32x4 acc[4][4] = {};

  for (int k0 = 0; k0 < K; k0 += 32) {
    if (Abf) {
#pragma unroll
      for (int p = 0; p < 2; ++p) {
        int rbase = p * 64 + wave * 16;
        gl_lds16(Abf + (size_t)(bm + rbase + grow) * K + k0 + gcol,
                 &As[rbase * 32]);
      }
    } else {
#pragma unroll
      for (int p = 0; p < 4; ++p) {
        int row = p * 32 + srow;
        float4 av = *reinterpret_cast<const float4*>(A + (size_t)(bm + row) * K + k0 + scol);
        uint2 aw; aw.x = pack2(av.x, av.y); aw.y = pack2(av.z, av.w);
        *reinterpret_cast<uint2*>(&As[row * 40 + scol]) = aw;
      }
    }
    if (Wbf) {
#pragma unroll
      for (int p = 0; p < 2; ++p) {
        int rbase = p * 64 + wave * 16;
        gl_lds16(Wbf + (size_t)(bn + rbase + grow) * K + k0 + gcol,
                 &Ws[rbase * 32]);
      }
    } else {
#pragma unroll
      for (int p = 0; p < 4; ++p) {
        int row = p * 32 + srow;
        float4 wv = *reinterpret_cast<const float4*>(W + (size_t)(bn + row) * K + k0 + scol);
        uint2 ww; ww.x = pack2(wv.x, wv.y); ww.y = pack2(wv.z, wv.w);
        *reinterpret_cast<uint2*>(&Ws[row * 40 + scol]) = ww;
      }
    }
    __syncthreads();
    short8v av[4], bv[4];
#pragma unroll
    for (int m = 0; m < 4; ++m)
      av[m] = *reinterpret_cast<const short8v*>(&As[(wr * 64 + m * 16 + lr) * PA + lk]);
#pragma unroll
    for (int n = 0; n < 4; ++n)
      bv[n] = *reinterpret_cast<const short8v*>(&Ws[(wc * 64 + n * 16 + lr) * PW + lk]);
#pragma unroll
    for (int m = 0; m < 4; ++m)
#pragma unroll
      for (int n = 0; n < 4; ++n)
        acc[m][n] = __builtin_amdgcn_mfma_f32_16x16x32_bf16(av[m], bv[n], acc[m][n], 0, 0, 0);
    __syncthreads();
  }

  const int rj = (lane >> 4) * 4;

  if (!Cb && !res) {
    // staged epilogue: As is dead after the k-loop; reuse as 16x128 fp32 tile
    float* Cs = (float*)As;           // 8192 B <= 10240 B
    const int rl = tid >> 5;          // 0..7
    const int cf = (tid & 31) * 4;    // 0..124
#pragma unroll
    for (int p = 0; p < 8; ++p) {
      __syncthreads();
      if (wr == (p >> 2)) {
        const int m = p & 3;
#pragma unroll
        for (int n = 0; n < 4; ++n)
#pragma unroll
          for (int j = 0; j < 4; ++j)
            Cs[(rj + j) * 128 + wc * 64 + n * 16 + lr] = acc[m][n][j];
      }
      __syncthreads();
#pragma unroll
      for (int rr = 0; rr < 2; ++rr) {
        int row_l = rr * 8 + rl;                 // 0..15
        float4 vv = *reinterpret_cast<const float4*>(&Cs[row_l * 128 + cf]);
        *reinterpret_cast<float4*>(&C[(size_t)(bm + p * 16 + row_l) * ldC + bn + cf]) = vv;
      }
    }
    return;
  }

#pragma unroll
  for (int m = 0; m < 4; ++m) {
    int rowb = bm + wr * 64 + m * 16 + rj;
#pragma unroll
    for (int n = 0; n < 4; ++n) {
      int col = bn + wc * 64 + n * 16 + lr;
#pragma unroll
      for (int j = 0; j < 4; ++j) {
        float v = acc[m][n][j];
        if (act == ACT_RELU2) { v = fmaxf(v, 0.f); v = v * v; }
        else if (act == ACT_SILU) { v = v / (1.f + expf(-v)); }
        if (Cb) {
          Cb[(size_t)(rowb + j) * ldC + col] = f2bf(v);
        } else {
          float* cp = C + (size_t)(rowb + j) * ldC + col;
          if (res) v += *cp;
          *cp = v;
        }
      }
    }
  }
}

// ---------------------------------------------------------------- merged QKV(+G) GEMM (bf16 A and W via gl_lds)
__global__ __launch_bounds__(256) void qkv_gemm_k(const ushort* __restrict__ Abf,
                                                  const ushort* __restrict__ W0,
                                                  const ushort* __restrict__ W1,
                                                  const ushort* __restrict__ W2,
                                                  const ushort* __restrict__ W3,
                                                  int p0, int p1, int p2,
                                                  float* __restrict__ C0,
                                                  float* __restrict__ C1,
                                                  float* __restrict__ C2,
                                                  float* __restrict__ C3,
                                                  int ldC0, int ldC1, int ldC2, int ldC3,
                                                  int cb0, int cb1, int cb2, int cb3,
                                                  int K) {
  __shared__ ushort As[128 * 32];
  __shared__ ushort Ws[128 * 32];
  const int pn = blockIdx.y;
  const ushort* W; float* C; int ldC; int colb; int dosilu = 0;
  if (pn < p0)      { W = W0 + (size_t)pn * 128 * K;        C = C0; ldC = ldC0; colb = cb0 + pn * 128; }
  else if (pn < p1) { W = W1 + (size_t)(pn - p0) * 128 * K; C = C1; ldC = ldC1; colb = cb1 + (pn - p0) * 128; }
  else if (pn < p2) { W = W2 + (size_t)(pn - p1) * 128 * K; C = C2; ldC = ldC2; colb = cb2 + (pn - p1) * 128; }
  else              { W = W3 + (size_t)(pn - p2) * 128 * K; C = C3; ldC = ldC3; colb = cb3 + (pn - p2) * 128; dosilu = 1; }
  const int bm = blockIdx.x * 128;
  const int tid = threadIdx.x;
  const int wave = tid >> 6, lane = tid & 63;
  const int wr = wave >> 1, wc = wave & 1;
  const int lr = lane & 15, lk = (lane >> 4) * 8;
  const int grow = lane >> 2;
  const int gcol = (lane & 3) * 8;

  f32x4 acc[4][4] = {};

  for (int k0 = 0; k0 < K; k0 += 32) {
#pragma unroll
    for (int p = 0; p < 2; ++p) {
      int rbase = p * 64 + wave * 16;
      gl_lds16(Abf + (size_t)(bm + rbase + grow) * K + k0 + gcol,
               &As[rbase * 32]);
      gl_lds16(W + (size_t)(rbase + grow) * K + k0 + gcol,
               &Ws[rbase * 32]);
    }
    __syncthreads();
    short8v av[4], bv[4];
#pragma unroll
    for (int m = 0; m < 4; ++m)
      av[m] = *reinterpret_cast<const short8v*>(&As[(wr * 64 + m * 16 + lr) * 32 + lk]);
#pragma unroll
    for (int n = 0; n < 4; ++n)
      bv[n] = *reinterpret_cast<const short8v*>(&Ws[(wc * 64 + n * 16 + lr) * 32 + lk]);
#pragma unroll
    for (int m = 0; m < 4; ++m)
#pragma unroll
      for (int n = 0; n < 4; ++n)
        acc[m][n] = __builtin_amdgcn_mfma_f32_16x16x32_bf16(av[m], bv[n], acc[m][n], 0, 0, 0);
    __syncthreads();
  }

  const int rj = (lane >> 4) * 4;
#pragma unroll
  for (int m = 0; m < 4; ++m) {
    int rowb = bm + wr * 64 + m * 16 + rj;
#pragma unroll
    for (int n = 0; n < 4; ++n) {
      int col = colb + wc * 64 + n * 16 + lr;
#pragma unroll
      for (int j = 0; j < 4; ++j) {
        float v = acc[m][n][j];
        if (dosilu) v = v / (1.f + expf(-v));
        C[(size_t)(rowb + j) * ldC + col] = v;
      }
    }
  }
}

// ---------------------------------------------------------------- fused alpha/beta sigmoid projection
__global__ __launch_bounds__(256) void ab_proj_k(const ushort* __restrict__ hb,
                                                 const float* __restrict__ za,
                                                 const float* __restrict__ zb,
                                                 float* __restrict__ alp,
                                                 float* __restrict__ bet) {
  const int tid = threadIdx.x;
  const int wave = tid >> 6, lane = tid & 63;
  const int l15 = lane & 15, lk = (lane >> 4) * 8;
  const int r0 = blockIdx.x * 64 + wave * 16;
  f32x4 accA = {}, accB = {};
  for (int k0 = 0; k0 < 1024; k0 += 32) {
    short8v a = *reinterpret_cast<const short8v*>(hb + (size_t)(r0 + l15) * 1024 + k0 + lk);
    const float* pa = za + l15 * 1024 + k0 + lk;
    const float* pb = zb + l15 * 1024 + k0 + lk;
    float4 xa = *reinterpret_cast<const float4*>(pa);
    float4 ya = *reinterpret_cast<const float4*>(pa + 4);
    float4 xb = *reinterpret_cast<const float4*>(pb);
    float4 yb = *reinterpret_cast<const float4*>(pb + 4);
    union { short8v v; uint u[4]; } ba, bb;
    ba.u[0] = pack2(xa.x, xa.y); ba.u[1] = pack2(xa.z, xa.w);
    ba.u[2] = pack2(ya.x, ya.y); ba.u[3] = pack2(ya.z, ya.w);
    bb.u[0] = pack2(xb.x, xb.y); bb.u[1] = pack2(xb.z, xb.w);
    bb.u[2] = pack2(yb.x, yb.y); bb.u[3] = pack2(yb.z, yb.w);
    accA = __builtin_amdgcn_mfma_f32_16x16x32_bf16(a, ba.v, accA, 0, 0, 0);
    accB = __builtin_amdgcn_mfma_f32_16x16x32_bf16(a, bb.v, accB, 0, 0, 0);
  }
  const int rj = (lane >> 4) * 4;
#pragma unroll
  for (int j = 0; j < 4; ++j) {
    int row = r0 + rj + j;
    alp[(size_t)row * 16 + l15] = 1.f / (1.f + expf(-accA[j]));
    bet[(size_t)row * 16 + l15] = 1.f / (1.f + expf(-accB[j]));
  }
}

// ---------------------------------------------------------------- l2norm (+gain) (+rope) on rows of 64
__global__ __launch_bounds__(256) void l2n_rope_k(float* __restrict__ P, int NH,
                                                  const float* __restrict__ gain,
                                                  const float* __restrict__ cosT,
                                                  const float* __restrict__ sinT,
                                                  int do_rope) {
  int row = blockIdx.x * 4 + (threadIdx.x >> 6);
  int lane = threadIdx.x & 63;
  size_t idx = (size_t)row * 64 + lane;
  float val = P[idx];
  float ss = val * val;
#pragma unroll
  for (int m = 1; m < 64; m <<= 1) ss += __shfl_xor(ss, m, 64);
  val = val / fmaxf(sqrtf(ss), 1e-6f);
  int hh = row % NH;
  int t = (row / NH) & (TT - 1);
  if (gain) val *= gain[hh];
  if (do_rope) {
    float pr = __shfl_xor(val, 32, 64);
    int jj = lane & 31;
    float c = cosT[t * 32 + jj];
    float s = sinT[t * 32 + jj];
    val = (lane < 32) ? (val * c + pr * s) : (val * c - pr * s);
  }
  P[idx] = val;
}

// ---------------------------------------------------------------- MFMA flash attention (bf16 pre-converted K/V; bf16 out)
__global__ __launch_bounds__(256) void attn_mfma_k(const float* __restrict__ Q,
                                                   const ushort* __restrict__ Kbb,
                                                   const ushort* __restrict__ Vtb,
                                                   ushort* __restrict__ Ob16) {
  __shared__ ushort Ks[64 * 72];
  __shared__ ushort Vt[64 * 72];
  __shared__ ushort Ps[4][16 * 72];

  const int q0 = blockIdx.x * 64;
  const int bh = blockIdx.y;
  const int b = bh >> 4, hh = bh & 15;
  const int kvh = hh >> 2;
  const int tid = threadIdx.x;
  const int wave = tid >> 6, lane = tid & 63;
  const int l15 = lane & 15, l16 = lane >> 4;   // 0..15 / 0..3
  const int rj = l16 * 4;

  const int qrs = HH * 64;    // 1024
  const int krs = KVH * 64;   // 256
  const float* Qb = Q + (size_t)b * TT * qrs + hh * 64;
  const ushort* Kb = Kbb + (size_t)b * TT * krs + kvh * 64;
  const ushort* Vb = Vtb + (size_t)(b * KVH + kvh) * 64 * TT;
  ushort* Ob = Ob16 + (size_t)b * TT * qrs + hh * 64;

  short8v qa[2];
  {
    const float* qp = Qb + (size_t)(q0 + wave * 16 + l15) * qrs + l16 * 8;
#pragma unroll
    for (int dblk = 0; dblk < 2; ++dblk) {
      float4 x = *reinterpret_cast<const float4*>(qp + dblk * 32);
      float4 y = *reinterpret_cast<const float4*>(qp + dblk * 32 + 4);
      union { short8v v; uint u[4]; } tmp;
      tmp.u[0] = pack2(x.x, x.y); tmp.u[1] = pack2(x.z, x.w);
      tmp.u[2] = pack2(y.x, y.y); tmp.u[3] = pack2(y.z, y.w);
      qa[dblk] = tmp.v;
    }
  }

  short8v ones;
  { union { short8v v; uint u[4]; } t;
    t.u[0] = t.u[1] = t.u[2] = t.u[3] = 0x3F803F80u; ones = t.v; }

  f32x4 o[4] = {};
  f32x4 denom = {};

  const int srow = tid >> 2;          // 0..63 (key for Ks, d for Vt)
  const int sc16 = (tid & 3) * 16;    // 16-ushort column base

  for (int kc = 0; kc <= q0; kc += 64) {
    __syncthreads();
    {
      const ushort* kp = Kb + (size_t)(kc + srow) * krs + sc16;
      *reinterpret_cast<short8v*>(&Ks[srow * 72 + sc16]) =
          *reinterpret_cast<const short8v*>(kp);
      *reinterpret_cast<short8v*>(&Ks[srow * 72 + sc16 + 8]) =
          *reinterpret_cast<const short8v*>(kp + 8);
      const ushort* vp = Vb + (size_t)srow * TT + kc + sc16;
      *reinterpret_cast<short8v*>(&Vt[srow * 72 + sc16]) =
          *reinterpret_cast<const short8v*>(vp);
      *reinterpret_cast<short8v*>(&Vt[srow * 72 + sc16 + 8]) =
          *reinterpret_cast<const short8v*>(vp + 8);
    }
    __syncthreads();

    // S = Q @ K^T (16q x 64k)
    f32x4 s[4];
#pragma unroll
    for (int kb = 0; kb < 4; ++kb) {
      short8v k0 = *reinterpret_cast<const short8v*>(&Ks[(kb * 16 + l15) * 72 + l16 * 8]);
      short8v k1 = *reinterpret_cast<const short8v*>(&Ks[(kb * 16 + l15) * 72 + 32 + l16 * 8]);
      f32x4 z = {};
      z = __builtin_amdgcn_mfma_f32_16x16x32_bf16(qa[0], k0, z, 0, 0, 0);
      s[kb] = __builtin_amdgcn_mfma_f32_16x16x32_bf16(qa[1], k1, z, 0, 0, 0);
    }

    // causal mask + exp -> Ps bf16
    const int qg = q0 + wave * 16 + rj;
#pragma unroll
    for (int kb = 0; kb < 4; ++kb) {
      int key = kc + kb * 16 + l15;
#pragma unroll
      for (int j = 0; j < 4; ++j) {
        float p = (key <= qg + j) ? __expf(s[kb][j]) : 0.f;
        Ps[wave][(rj + j) * 72 + kb * 16 + l15] = f2bf(p);
      }
    }

    short8v pa0 = *reinterpret_cast<const short8v*>(&Ps[wave][l15 * 72 + l16 * 8]);
    short8v pa1 = *reinterpret_cast<const short8v*>(&Ps[wave][l15 * 72 + 32 + l16 * 8]);

    f32x4 dz = {};
    dz = __builtin_amdgcn_mfma_f32_16x16x32_bf16(pa0, ones, dz, 0, 0, 0);
    dz = __builtin_amdgcn_mfma_f32_16x16x32_bf16(pa1, ones, dz, 0, 0, 0);
    denom += dz;

#pragma unroll
    for (int db = 0; db < 4; ++db) {
      short8v v0 = *reinterpret_cast<const short8v*>(&Vt[(db * 16 + l15) * 72 + l16 * 8]);
      short8v v1 = *reinterpret_cast<const short8v*>(&Vt[(db * 16 + l15) * 72 + 32 + l16 * 8]);
      o[db] = __builtin_amdgcn_mfma_f32_16x16x32_bf16(pa0, v0, o[db], 0, 0, 0);
      o[db] = __builtin_amdgcn_mfma_f32_16x16x32_bf16(pa1, v1, o[db], 0, 0, 0);
    }
  }

  const int qg = q0 + wave * 16 + rj;
#pragma unroll
  for (int j = 0; j < 4; ++j) {
    float inv = 1.0f / denom[j];
    ushort* op = Ob + (size_t)(qg + j) * qrs;
#pragma unroll
    for (int db = 0; db < 4; ++db) op[db * 16 + l15] = f2bf(o[db][j] * inv);
  }
}

// ---------------------------------------------------------------- causal depthwise conv (CK=4) + silu + split
__global__ __launch_bounds__(256) void conv_k(const float* __restrict__ X,
                                              const float* __restrict__ Wc,
                                              float* __restrict__ Qo,
                                              float* __restrict__ Ko,
                                              float* __restrict__ Vo) {
  int idx = blockIdx.x * 256 + threadIdx.x;   // B*T*3072 exact
  int c = idx % 3072;
  int rest = idx / 3072;
  int t = rest & (TT - 1);
  int b = rest >> 10;
  const float* w = Wc + c * 4;
  float acc = 0.f;
#pragma unroll
  for (int j = 0; j < 4; ++j) {
    int tt = t - 3 + j;
    if (tt >= 0) acc += w[j] * X[((size_t)(b * TT + tt)) * 3072 + c];
  }
  float y = acc / (1.f + expf(-acc));   // silu
  int which = c >> 10, cc = c & 1023;
  float* dst = (which == 0) ? Qo : ((which == 1) ? Ko : Vo);
  dst[((size_t)(b * TT + t)) * 1024 + cc] = y;
}

// ---------------------------------------------------------------- GDN segmented scan
__global__ __launch_bounds__(256) void gdn_p1_k(const float* __restrict__ Kg,
                                                const float* __restrict__ Vg,
                                                const float* __restrict__ Al,
                                                const float* __restrict__ Be,
                                                float* __restrict__ Aseg,
                                                float* __restrict__ Useg) {
  __shared__ float Kl[2][CH * 64];
  __shared__ float Vl[2][CH * 64];
  __shared__ float As_[2][CH];
  __shared__ float Bs_[2][CH];

  const int seg = blockIdx.x;            // 0..7
  const int bh = blockIdx.y;             // 0..31
  const int basis = (blockIdx.z == 0);
  const int b = bh >> 4, hh = bh & 15;
  const int tid = threadIdx.x;
  const int wave = tid >> 6;
  const int lane = tid & 63;
  const int vloc = lane >> 2;
  const int dgrp = lane & 3;
  const int d0 = dgrp * 16;
  const int v = wave * 16 + vloc;

  const size_t base = (size_t)b * TT * 1024 + hh * 64 + (size_t)seg * SEGL * 1024;
  const size_t ab0 = (size_t)b * TT * HH + hh + (size_t)seg * SEGL * HH;

  const int s_step = tid >> 4;
  const int s_col = (tid & 15) * 4;

  float S[16];
#pragma unroll
  for (int i = 0; i < 16; ++i) S[i] = (basis && (d0 + i == v)) ? 1.f : 0.f;

  float4 kst[2], vst[2];
  float ast = 0.f, bst = 0.f;

#define ISSUE(c0)                                                              \
  {                                                                            \
    _Pragma("unroll") for (int p = 0; p < 2; ++p) {                            \
      int st = p * 16 + s_step;                                                \
      size_t off = base + (size_t)((c0) + st) * 1024 + s_col;                  \
      kst[p] = *reinterpret_cast<const float4*>(Kg + off);                     \
      if (!basis) vst[p] = *reinterpret_cast<const float4*>(Vg + off);         \
    }                                                                          \
    if (tid < CH) ast = Al[ab0 + (size_t)((c0) + tid) * HH];                   \
    else if (tid < 2 * CH) bst = Be[ab0 + (size_t)((c0) + tid - CH) * HH];     \
  }

#define WRITE(ib)                                                              \
  {                                                                            \
    _Pragma("unroll") for (int p = 0; p < 2; ++p) {                            \
      int st = p * 16 + s_step;                                                \
      *reinterpret_cast<float4*>(&Kl[ib][st * 64 + s_col]) = kst[p];           \
      if (!basis) *reinterpret_cast<float4*>(&Vl[ib][st * 64 + s_col]) = vst[p];\
    }                                                                          \
    if (tid < CH) As_[ib][tid] = ast;                                          \
    else if (tid < 2 * CH) Bs_[ib][tid - CH] = bst;                            \
  }

#define LOADL(KX, VX, AX, BX, ib, tt)                                          \
  {                                                                            \
    const float* kp = &Kl[ib][(tt) * 64 + d0];                                 \
    _Pragma("unroll") for (int i = 0; i < 4; ++i) {                            \
      float4 kv = *reinterpret_cast<const float4*>(kp + i * 4);                \
      KX[4 * i] = kv.x; KX[4 * i + 1] = kv.y;                                  \
      KX[4 * i + 2] = kv.z; KX[4 * i + 3] = kv.w;                              \
    }                                                                          \
    VX = basis ? 0.f : Vl[ib][(tt) * 64 + v];                                  \
    AX = As_[ib][(tt)];                                                        \
    BX = Bs_[ib][(tt)];                                                        \
  }

#define STEP(KX, VX, AX, BX)                                                   \
  {                                                                            \
    float t0 = 0.f, t1 = 0.f, t2 = 0.f, t3 = 0.f;                              \
    _Pragma("unroll") for (int i = 0; i < 16; i += 4) {                        \
      t0 += KX[i] * S[i];                                                      \
      t1 += KX[i + 1] * S[i + 1];                                              \
      t2 += KX[i + 2] * S[i + 2];                                              \
      t3 += KX[i + 3] * S[i + 3];                                              \
    }                                                                          \
    float ks = qadd4((t0 + t1) + (t2 + t3));                                   \
    float cin = VX - AX * BX * ks;                                             \
    _Pragma("unroll") for (int i = 0; i < 16; ++i)                             \
      S[i] = AX * S[i] + cin * KX[i];                                          \
  }

  float kA[16], kB[16];
  float vA, aA, btA, vB, aB, btB;

  const int NC = SEGL / CH;   // 4 chunks
  ISSUE(0);
  WRITE(0);
  __syncthreads();
  ISSUE(CH);
  for (int cnk = 0; cnk < NC; ++cnk) {
    const int ib = cnk & 1;
    LOADL(kA, vA, aA, btA, ib, 0);
    for (int t = 0; t < CH; t += 2) {
      LOADL(kB, vB, aB, btB, ib, t + 1);
      STEP(kA, vA, aA, btA);
      if (t + 2 < CH) LOADL(kA, vA, aA, btA, ib, t + 2);
      STEP(kB, vB, aB, btB);
    }
    if (cnk + 1 < NC) {
      WRITE(ib ^ 1);
      __syncthreads();
      if (cnk + 2 < NC) ISSUE((cnk + 2) * CH);
    }
  }
#undef ISSUE
#undef WRITE
#undef LOADL
#undef STEP

  float* dst = (basis ? Aseg : Useg) + (size_t)(bh * 8 + seg) * 4096;
#pragma unroll
  for (int i = 0; i < 16; ++i) dst[(d0 + i) * 64 + v] = S[i];
}

__global__ __launch_bounds__(256) void gdn_p2_k(const float* __restrict__ Aseg,
                                                const float* __restrict__ Useg,
                                                float* __restrict__ S0) {
  __shared__ float Sc[4096];
  const int bh = blockIdx.x;
  const int tid = threadIdx.x;
  for (int i = tid; i < 4096; i += 256) Sc[i] = 0.f;
  __syncthreads();
  const int dr = tid >> 2;         // 0..63 (row)
  const int v4 = (tid & 3) * 16;   // col base
  for (int s = 0; s < 8; ++s) {
    for (int i = tid; i < 4096; i += 256) S0[(size_t)(bh * 8 + s) * 4096 + i] = Sc[i];
    if (s == 7) break;
    const float* Arow = Aseg + (size_t)(bh * 8 + s) * 4096 + dr * 64;
    const float* Up = Useg + (size_t)(bh * 8 + s) * 4096 + dr * 64 + v4;
    float acc[16];
#pragma unroll
    for (int i = 0; i < 16; ++i) acc[i] = Up[i];
    for (int j = 0; j < 64; ++j) {
      float a = Arow[j];
      const float* sr = &Sc[j * 64 + v4];
#pragma unroll
      for (int i = 0; i < 16; ++i) acc[i] += a * sr[i];
    }
    __syncthreads();
#pragma unroll
    for (int i = 0; i < 16; ++i) Sc[dr * 64 + v4 + i] = acc[i];
    __syncthreads();
  }
}

__global__ __launch_bounds__(256) void gdn_p3_k(const float* __restrict__ Qg,
                                                const float* __restrict__ Kg,
                                                const float* __restrict__ Vg,
                                                const float* __restrict__ Al,
                                                const float* __restrict__ Be,
                                                const float* __restrict__ S0,
                                                float* __restrict__ Og) {
  __shared__ float Kl[2][CH * 64];
  __shared__ float Ql[2][CH * 64];
  __shared__ float Vl[2][CH * 64];
  __shared__ float As_[2][CH];
  __shared__ float Bs_[2][CH];

  const int seg = blockIdx.x;            // 0..7
  const int bh = blockIdx.y;             // 0..31
  const int b = bh >> 4, hh = bh & 15;
  const int tid = threadIdx.x;
  const int wave = tid >> 6;
  const int lane = tid & 63;
  const int vloc = lane >> 2;
  const int dgrp = lane & 3;
  const int d0 = dgrp * 16;
  const int v = wave * 16 + vloc;

  const size_t base = (size_t)b * TT * 1024 + hh * 64 + (size_t)seg * SEGL * 1024;
  const size_t ab0 = (size_t)b * TT * HH + hh + (size_t)seg * SEGL * HH;

  const int s_step = tid >> 4;
  const int s_col = (tid & 15) * 4;

  float S[16];
  {
    const float* sp = S0 + (size_t)(bh * 8 + seg) * 4096;
#pragma unroll
    for (int i = 0; i < 16; ++i) S[i] = sp[(d0 + i) * 64 + v];
  }

  float4 kst[2], qst[2], vst[2];
  float ast = 0.f, bst = 0.f;

#define ISSUE(c0)                                                              \
  {                                                                            \
    _Pragma("unroll") for (int p = 0; p < 2; ++p) {                            \
      int st = p * 16 + s_step;                                                \
      size_t off = base + (size_t)((c0) + st) * 1024 + s_col;                  \
      kst[p] = *reinterpret_cast<const float4*>(Kg + off);                     \
      qst[p] = *reinterpret_cast<const float4*>(Qg + off);                     \
      vst[p] = *reinterpret_cast<const float4*>(Vg + off);                     \
    }                                                                          \
    if (tid < CH) ast = Al[ab0 + (size_t)((c0) + tid) * HH];                   \
    else if (tid < 2 * CH) bst = Be[ab0 + (size_t)((c0) + tid - CH) * HH];     \
  }

#define WRITE(ib)                                                              \
  {                                                                            \
    _Pragma("unroll") for (int p = 0; p < 2; ++p) {                            \
      int st = p * 16 + s_step;                                                \
      *reinterpret_cast<float4*>(&Kl[ib][st * 64 + s_col]) = kst[p];           \
      *reinterpret_cast<float4*>(&Ql[ib][st * 64 + s_col]) = qst[p];           \
      *reinterpret_cast<float4*>(&Vl[ib][st * 64 + s_col]) = vst[p];           \
    }                                                                          \
    if (tid < CH) As_[ib][tid] = ast;                                          \
    else if (tid < 2 * CH) Bs_[ib][tid - CH] = bst;                            \
  }

#define LOADL(KX, QX, VX, AX, BX, ib, tt)                                      \
  {                                                                            \
    const float* kp = &Kl[ib][(tt) * 64 + d0];                                 \
    const float* qp = &Ql[ib][(tt) * 64 + d0];                                 \
    _Pragma("unroll") for (int i = 0; i < 4; ++i) {                            \
      float4 kv = *reinterpret_cast<const float4*>(kp + i * 4);                \
      KX[4 * i] = kv.x; KX[4 * i + 1] = kv.y;                                  \
      KX[4 * i + 2] = kv.z; KX[4 * i + 3] = kv.w;                              \
      float4 qv = *reinterpret_cast<const float4*>(qp + i * 4);                \
      QX[4 * i] = qv.x; QX[4 * i + 1] = qv.y;                                  \
      QX[4 * i + 2] = qv.z; QX[4 * i + 3] = qv.w;                              \
    }                                                                          \
    VX = Vl[ib][(tt) * 64 + v];                                                \
    AX = As_[ib][(tt)];                                                        \
    BX = Bs_[ib][(tt)];                                                        \
  }

#define STEP(KX, QX, VX, AX, BX, gt)                                           \
  {                                                                            \
    float t0 = 0.f, t1 = 0.f, t2 = 0.f, t3 = 0.f;                              \
    _Pragma("unroll") for (int i = 0; i < 16; i += 4) {                        \
      t0 += KX[i] * S[i];                                                      \
      t1 += KX[i + 1] * S[i + 1];                                              \
      t2 += KX[i + 2] * S[i + 2];                                              \
      t3 += KX[i + 3] * S[i + 3];                                              \
    }                                                                          \
    float ks = qadd4((t0 + t1) + (t2 + t3));                                   \
    float cin = VX - AX * BX * ks;                                             \
    float o0 = 0.f, o1 = 0.f, o2 = 0.f, o3 = 0.f;                              \
    _Pragma("unroll") for (int i = 0; i < 16; i += 4) {                        \
      S[i] = AX * S[i] + cin * KX[i];               o0 += QX[i] * S[i];        \
      S[i + 1] = AX * S[i + 1] + cin * KX[i + 1];   o1 += QX[i + 1] * S[i + 1];\
      S[i + 2] = AX * S[i + 2] + cin * KX[i + 2];   o2 += QX[i + 2] * S[i + 2];\
      S[i + 3] = AX * S[i + 3] + cin * KX[i + 3];   o3 += QX[i + 3] * S[i + 3];\
    }                                                                          \
    float o = qadd4((o0 + o1) + (o2 + o3));                                    \
    if (dgrp == 0) Og[base + (size_t)(gt) * 1024 + v] = o;                     \
  }

  float kA[16], qA[16], kB[16], qB[16];
  float vA, aA, btA, vB, aB, btB;

  const int NC = SEGL / CH;   // 4 chunks
  ISSUE(0);
  WRITE(0);
  __syncthreads();
  ISSUE(CH);
  for (int cnk = 0; cnk < NC; ++cnk) {
    const int ib = cnk & 1;
    LOADL(kA, qA, vA, aA, btA, ib, 0);
    for (int t = 0; t < CH; t += 2) {
      LOADL(kB, qB, vB, aB, btB, ib, t + 1);
      STEP(kA, qA, vA, aA, btA, cnk * CH + t);
      if (t + 2 < CH) LOADL(kA, qA, vA, aA, btA, ib, t + 2);
      STEP(kB, qB, vB, aB, btB, cnk * CH + t + 1);
    }
    if (cnk + 1 < NC) {
      WRITE(ib ^ 1);
      __syncthreads();
      if (cnk + 2 < NC) ISSUE((cnk + 2) * CH);
    }
  }
#undef ISSUE
#undef WRITE
#undef LOADL
#undef STEP
}

// ---------------------------------------------------------------- rmsnorm over 64 * gate -> bf16 out
__global__ __launch_bounds__(256) void rms64_mul_k(const float* __restrict__ O,
                                                   const float* __restrict__ G,
                                                   ushort* __restrict__ Ob) {
  int row = blockIdx.x * 4 + (threadIdx.x >> 6);
  int lane = threadIdx.x & 63;
  size_t idx = (size_t)row * 64 + lane;
  float val = O[idx];
  float ss = val * val;
#pragma unroll
  for (int m = 1; m < 64; m <<= 1) ss += __shfl_xor(ss, m, 64);
  float sc = rsqrtf(ss * (1.0f / 64.0f) + 1e-6f);
  Ob[idx] = f2bf(val * sc * G[idx]);
}

// ---------------------------------------------------------------- host-side launch
static inline void gemm(hipStream_t s, const float* A, const ushort* Abf,
                        const float* W, const ushort* Wbf, float* C, ushort* Cb,
                        int M, int N, int K, int ldC, int act, int res) {
  int swap = (N >= 2048) ? 1 : 0;
  dim3 g = swap ? dim3(M / 128, N / 128) : dim3(N / 128, M / 128);
  mfma_gemm_k<<<g, 256, 0, s>>>(A, Abf, W, Wbf, C, Cb, M, N, K, ldC, act, res, swap);
}

extern "C" void kernel_launch(void* const* d_in, const int* in_sizes, int n_in,
                              void* d_out, int out_size, void* d_ws, size_t ws_size,
                              hipStream_t stream) {
  const int*   tokens = (const int*)d_in[0];
  const float* emb    = (const float*)d_in[1];
  const float* aw_q   = (const float*)d_in[2];
  const float* aw_k   = (const float*)d_in[3];
  const float* aw_v   = (const float*)d_in[4];
  const float* aw_o   = (const float*)d_in[5];
  const float* a_gain = (const float*)d_in[6];
  const float* a_m1   = (const float*)d_in[7];
  const float* a_m2   = (const float*)d_in[8];
  const float* g_wq   = (const float*)d_in[9];
  const float* g_wk   = (const float*)d_in[10];
  const float* g_wv   = (const float*)d_in[11];
  const float* g_wa   = (const float*)d_in[12];
  const float* g_wb   = (const float*)d_in[13];
  const float* g_wg   = (const float*)d_in[14];
  const float* g_wo   = (const float*)d_in[15];
  const float* g_conv = (const float*)d_in[16];
  const float* g_m1   = (const float*)d_in[17];
  const float* g_m2   = (const float*)d_in[18];

  const int M = BB * TT;  // 2048

  // ---- d_out scratch (fully rewritten by the final logits GEMM; nothing here read during it)
  float* outF = (float*)d_out;
  ushort* midb = (ushort*)outF;              // [0, 4194304) floats as bf16 M*DFF
  float* scanA = outF + 4194304;             // 1048576 (gdn A_seg)
  float* scanU = scanA + 1048576;            // 1048576 (gdn U_seg)
  float* scanS = scanU + 1048576;            // 1048576 (gdn S0)
  ushort* kbb = (ushort*)(outF + 7340032);   // 524288 ushorts (bf16 attn K)
  ushort* vtb = kbb + 524288;                // 524288 ushorts (bf16 attn V^T)
  float* qkv  = outF + 8388608;              // [8388608, 14680064)  B*T*3072
  ushort* hb  = (ushort*)(outF + 14680064);  // [14680064, 15728640) bf16 h

  // bf16 weight cache [15728640, 40370176)
  ushort* wtb = (ushort*)(outF + 15728640);
  ushort* awq_b = wtb;                 // 2097152 (both layers)
  ushort* awk_b = awq_b + 2097152;     // 524288
  ushort* awv_b = awk_b + 524288;      // 524288
  ushort* awo_b = awv_b + 524288;      // 2097152
  ushort* am1_b = awo_b + 2097152;     // 8388608
  ushort* am2_b = am1_b + 8388608;     // 8388608
  ushort* gwq_b = am2_b + 8388608;     // 2097152
  ushort* gwk_b = gwq_b + 2097152;     // 2097152
  ushort* gwv_b = gwk_b + 2097152;     // 2097152
  ushort* gwg_b = gwv_b + 2097152;     // 2097152
  ushort* gwo_b = gwg_b + 2097152;     // 2097152
  ushort* gm1_b = gwo_b + 2097152;     // 8388608
  ushort* gm2_b = gm1_b + 8388608;     // 8388608  (ends at float 40370176)

  // per-layer activations [40370176, ...); qgb/ogb are M*1024 = 2097152 ushorts each
  float* qb   = outF + 40370176;             // 2097152 -> ends 42467328
  float* kb   = qb + 2097152;                // 524288  -> ends 42991616
  float* vb   = kb + 524288;                 // 524288  -> ends 43515904
  float* qg   = vb + 524288;                 // 2097152 -> ends 45613056
  float* kg   = qg + 2097152;                // 2097152 -> ends 47710208
  float* vg   = kg + 2097152;                // 2097152 -> ends 49807360
  float* og   = vg + 2097152;                // 2097152 -> ends 51904512
  float* gb   = og + 2097152;                // 2097152 -> ends 54001664
  ushort* qgb = (ushort*)(gb + 2097152);     // 2097152 ushorts -> float [54001664, 55050240)
  ushort* ogb = qgb + 2097152;               // 2097152 ushorts -> float [55050240, 56098816)
  float* x    = outF + 56098816;             // 2097152 -> ends 58195968
  float* alp  = outF + 58195968;             // 32768
  float* bet  = alp + 32768;                 // 32768
  float* cosT = bet + 32768;                 // 32768
  float* sinT = cosT + 32768;                // 32768 -> ends 58327040
  float* h    = outF + 58327040;             // 2097152 -> ends 60424192 (< 67108864)

  // ---- ws: {embb, hbL} = 71,303,168 B (within the 71,827,456 B footprint
  // proven safe by rounds 1-19).
  ushort* embb = (ushort*)d_ws;                 // VV*DD ushorts (64 MiB)
  ushort* hbL  = embb + (size_t)VV * DD;        // M*DD ushorts (4 MB)

  rope_tab_k<<<128, 256, 0, stream>>>(cosT, sinT);
  embed_k<<<M, 256, 0, stream>>>(tokens, emb, x);
  cvt_bf_k<<<2048, 256, 0, stream>>>(emb, embb, (VV * DD) / 8);

  // pre-convert all layer weights to bf16 (one-time per launch)
  cvt_bf_k<<<1024, 256, 0, stream>>>(aw_q, awq_b, 2097152 / 8);
  cvt_bf_k<<<512, 256, 0, stream>>>(aw_k, awk_b, 524288 / 8);
  cvt_bf_k<<<512, 256, 0, stream>>>(aw_v, awv_b, 524288 / 8);
  cvt_bf_k<<<1024, 256, 0, stream>>>(aw_o, awo_b, 2097152 / 8);
  cvt_bf_k<<<2048, 256, 0, stream>>>(a_m1, am1_b, 8388608 / 8);
  cvt_bf_k<<<2048, 256, 0, stream>>>(a_m2, am2_b, 8388608 / 8);
  cvt_bf_k<<<1024, 256, 0, stream>>>(g_wq, gwq_b, 2097152 / 8);
  cvt_bf_k<<<1024, 256, 0, stream>>>(g_wk, gwk_b, 2097152 / 8);
  cvt_bf_k<<<1024, 256, 0, stream>>>(g_wv, gwv_b, 2097152 / 8);
  cvt_bf_k<<<1024, 256, 0, stream>>>(g_wg, gwg_b, 2097152 / 8);
  cvt_bf_k<<<1024, 256, 0, stream>>>(g_wo, gwo_b, 2097152 / 8);
  cvt_bf_k<<<2048, 256, 0, stream>>>(g_m1, gm1_b, 8388608 / 8);
  cvt_bf_k<<<2048, 256, 0, stream>>>(g_m2, gm2_b, 8388608 / 8);

  for (int i = 0; i < 2; ++i) {
    const float* za = g_wa + (size_t)i * 16 * 1024;
    const float* zb = g_wb + (size_t)i * 16 * 1024;
    const float* zc = g_conv + (size_t)i * 3072 * 4;
    const ushort* wq_b = awq_b + (size_t)i * 1048576;
    const ushort* wk_b = awk_b + (size_t)i * 262144;
    const ushort* wv_b = awv_b + (size_t)i * 262144;
    const ushort* wo_b = awo_b + (size_t)i * 1048576;
    const ushort* m1_b = am1_b + (size_t)i * 4194304;
    const ushort* m2_b = am2_b + (size_t)i * 4194304;
    const ushort* zq_b = gwq_b + (size_t)i * 1048576;
    const ushort* zk_b = gwk_b + (size_t)i * 1048576;
    const ushort* zv_b = gwv_b + (size_t)i * 1048576;
    const ushort* zg_b = gwg_b + (size_t)i * 1048576;
    const ushort* zo_b = gwo_b + (size_t)i * 1048576;
    const ushort* n1_b = gm1_b + (size_t)i * 4194304;
    const ushort* n2_b = gm2_b + (size_t)i * 4194304;

    // ---------------- attention block ----------------
    rmsnorm_k<<<M, 256, 0, stream>>>(x, h, hb);
    qkv_gemm_k<<<dim3(M / 128, 12), 256, 0, stream>>>(
        hb, wq_b, wk_b, wv_b, nullptr, 8, 10, 12,
        qb, kb, vb, nullptr, 1024, 256, 256, 0, 0, 0, 0, 0, 1024);
    l2n_rope_k<<<(M * HH) / 4, 256, 0, stream>>>(qb, HH, a_gain + (size_t)i * 16, cosT, sinT, 1);
    l2n_rope_k<<<(M * KVH) / 4, 256, 0, stream>>>(kb, KVH, nullptr, cosT, sinT, 1);
    cvt_bf_k<<<256, 256, 0, stream>>>(kb, kbb, (M * 256) / 8);
    cvt_vt_k<<<2048, 256, 0, stream>>>(vb, vtb);
    attn_mfma_k<<<dim3(TT / 64, BB * HH), 256, 0, stream>>>(qb, kbb, vtb, qgb);
    gemm(stream, nullptr, qgb, nullptr, wo_b, x, nullptr, M, 1024, 1024, 1024, ACT_NONE, 1);
    rmsnorm_k<<<M, 256, 0, stream>>>(x, h, hb);
    gemm(stream, nullptr, hb, nullptr, m1_b, nullptr, midb, M, DFF, 1024, DFF, ACT_RELU2, 0);
    gemm(stream, nullptr, midb, nullptr, m2_b, x, nullptr, M, 1024, DFF, 1024, ACT_NONE, 1);

    // ---------------- GDN block ----------------
    rmsnorm_k<<<M, 256, 0, stream>>>(x, h, hb);
    qkv_gemm_k<<<dim3(M / 128, 32), 256, 0, stream>>>(
        hb, zq_b, zk_b, zv_b, zg_b, 8, 16, 24,
        qkv, qkv, qkv, gb, 3072, 3072, 3072, 1024, 0, 1024, 2048, 0, 1024);
    conv_k<<<(M * 3072) / 256, 256, 0, stream>>>(qkv, zc, qg, kg, vg);
    l2n_rope_k<<<(M * HH) / 4, 256, 0, stream>>>(qg, HH, nullptr, nullptr, nullptr, 0);
    l2n_rope_k<<<(M * HH) / 4, 256, 0, stream>>>(kg, HH, nullptr, nullptr, nullptr, 0);
    ab_proj_k<<<M / 64, 256, 0, stream>>>(hb, za, zb, alp, bet);
    gdn_p1_k<<<dim3(8, BB * HH, 2), 256, 0, stream>>>(kg, vg, alp, bet, scanA, scanU);
    gdn_p2_k<<<BB * HH, 256, 0, stream>>>(scanA, scanU, scanS);
    gdn_p3_k<<<dim3(8, BB * HH), 256, 0, stream>>>(qg, kg, vg, alp, bet, scanS, og);
    rms64_mul_k<<<(M * HH) / 4, 256, 0, stream>>>(og, gb, ogb);
    gemm(stream, nullptr, ogb, nullptr, zo_b, x, nullptr, M, 1024, 1024, 1024, ACT_NONE, 1);
    rmsnorm_k<<<M, 256, 0, stream>>>(x, h, hb);
    gemm(stream, nullptr, hb, nullptr, n1_b, nullptr, midb, M, DFF, 1024, DFF, ACT_RELU2, 0);
    gemm(stream, nullptr, midb, nullptr, n2_b, x, nullptr, M, 1024, DFF, 1024, ACT_NONE, 1);
  }

  // ---------------- final logits: A = hbL (bf16, ws), W = embb (bf16, ws).
  rmsnorm_k<<<M, 256, 0, stream>>>(x, h, hbL);
  gemm(stream, nullptr, hbL, nullptr, embb, outF, nullptr, M, VV, 1024, VV, ACT_NONE, 0);
}

// Round 30
// 1814.582 us; speedup vs baseline: 1.1037x; 1.0183x over previous
//
#include <hip/hip_runtime.h>
#include <hip/hip_bf16.h>
#include <math.h>

// ---------------------------------------------------------------- constants
#define BB 2
#define TT 1024
#define DD 1024
#define HH 16
#define KVH 4
#define HDIM 64
#define VV 32768
#define DFF 4096
#define CH 32    // gdn scan chunk (steps staged in LDS per buffer)
#define SEGL 128 // gdn segmented-scan segment length (8 segments)

#define ACT_NONE 0
#define ACT_RELU2 1
#define ACT_SILU 2
#define ACT_SIG 3

typedef __attribute__((ext_vector_type(8))) short short8v;
typedef __attribute__((ext_vector_type(4))) float f32x4;

__device__ inline ushort f2bf(float f) {
  uint u = __float_as_uint(f);
  uint r = u + 0x7FFFu + ((u >> 16) & 1u);
  return (ushort)(r >> 16);
}
__device__ inline uint pack2(float lo, float hi) {
  return (uint)f2bf(lo) | ((uint)f2bf(hi) << 16);
}

// 4-lane (quad) sum via DPP quad_perm: xor1 (0xB1) then xor2 (0x4E). VALU-speed.
__device__ inline float qadd4(float x) {
  float y = __int_as_float(__builtin_amdgcn_update_dpp(
      0, __float_as_int(x), 0xB1, 0xF, 0xF, true));
  x += y;
  float z = __int_as_float(__builtin_amdgcn_update_dpp(
      0, __float_as_int(x), 0x4E, 0xF, 0xF, true));
  return x + z;
}

// async global->LDS, 16B/lane: dst = wave-uniform LDS base + lane*16
__device__ inline void gl_lds16(const void* g, void* l) {
  __builtin_amdgcn_global_load_lds(
      (const __attribute__((address_space(1))) void*)g,
      (__attribute__((address_space(3))) void*)l, 16, 0, 0);
}

// ---------------------------------------------------------------- f32 -> bf16 bulk convert
__global__ __launch_bounds__(256) void cvt_bf_k(const float* __restrict__ src,
                                                ushort* __restrict__ dst, int n8) {
  for (int i = blockIdx.x * 256 + threadIdx.x; i < n8; i += gridDim.x * 256) {
    const float4 a = *reinterpret_cast<const float4*>(src + (size_t)i * 8);
    const float4 b = *reinterpret_cast<const float4*>(src + (size_t)i * 8 + 4);
    uint4 o;
    o.x = pack2(a.x, a.y); o.y = pack2(a.z, a.w);
    o.z = pack2(b.x, b.y); o.w = pack2(b.z, b.w);
    *reinterpret_cast<uint4*>(dst + (size_t)i * 8) = o;
  }
}

// ---------------------------------------------------------------- V transpose+convert: vtb[b][kvh][d][t] = bf16(vb[b][t][kvh*64+d])
__global__ __launch_bounds__(256) void cvt_vt_k(const float* __restrict__ vb,
                                                ushort* __restrict__ vtb) {
  int idx = blockIdx.x * 256 + threadIdx.x;   // B*KVH*64*1024 = 524288
  int t = idx & 1023;
  int rest = idx >> 10;
  int d = rest & 63;
  int bk = rest >> 6;        // b*KVH + kvh
  int b = bk >> 2, kvh = bk & 3;
  float v = vb[((size_t)(b * TT + t)) * 256 + kvh * 64 + d];
  vtb[idx] = f2bf(v);
}

// ---------------------------------------------------------------- rope tables
__global__ __launch_bounds__(256) void rope_tab_k(float* __restrict__ cosT,
                                                  float* __restrict__ sinT) {
  int idx = blockIdx.x * 256 + threadIdx.x;   // T*32 = 32768 total
  int t = idx >> 5, j = idx & 31;
  float inv = 1.0f / powf(10000.0f, (float)(2 * j) * (1.0f / 64.0f));
  float fr = (float)t * inv;
  cosT[idx] = cosf(fr);
  sinT[idx] = sinf(fr);
}

// ---------------------------------------------------------------- embedding gather
__global__ __launch_bounds__(256) void embed_k(const int* __restrict__ tok,
                                               const float* __restrict__ emb,
                                               float* __restrict__ X) {
  int row = blockIdx.x;          // B*T rows
  int tid = threadIdx.x;
  int tk = tok[row];
  float4 v = *reinterpret_cast<const float4*>(emb + (size_t)tk * DD + tid * 4);
  *reinterpret_cast<float4*>(X + (size_t)row * DD + tid * 4) = v;
}

// ---------------------------------------------------------------- rmsnorm over D=1024 (fp32 out optional; bf16 out)
__global__ __launch_bounds__(256) void rmsnorm_k(const float* __restrict__ in,
                                                 float* __restrict__ out,
                                                 ushort* __restrict__ outb) {
  int row = blockIdx.x;
  int tid = threadIdx.x;
  const float* p = in + (size_t)row * DD;
  float4 v = *reinterpret_cast<const float4*>(p + tid * 4);
  float ss = v.x * v.x + v.y * v.y + v.z * v.z + v.w * v.w;
#pragma unroll
  for (int m = 1; m < 64; m <<= 1) ss += __shfl_xor(ss, m, 64);
  __shared__ float wsum[4];
  int wid = tid >> 6, lane = tid & 63;
  if (lane == 0) wsum[wid] = ss;
  __syncthreads();
  float tot = wsum[0] + wsum[1] + wsum[2] + wsum[3];
  float sc = rsqrtf(tot * (1.0f / 1024.0f) + 1e-6f);
  float4 o;
  o.x = v.x * sc; o.y = v.y * sc; o.z = v.z * sc; o.w = v.w * sc;
  if (out)
    *reinterpret_cast<float4*>(out + (size_t)row * DD + tid * 4) = o;
  if (outb) {
    uint2 t; t.x = pack2(o.x, o.y); t.y = pack2(o.z, o.w);
    *reinterpret_cast<uint2*>(outb + (size_t)row * DD + tid * 4) = t;
  }
}

// ---------------------------------------------------------------- MFMA bf16 GEMM: C = [res +] act(A @ W^T)
// swapg: 0 = n-fastest grid; 1 = m-fastest (W reuse in L2/L3).
// The plain fp32-C no-res path (logits) stages the C tile through LDS and
// emits fully-coalesced cached float4 rows (verified R26: logits 255->233us).
__global__ __launch_bounds__(256) void mfma_gemm_k(const float* __restrict__ A,
                                                   const ushort* __restrict__ Abf,
                                                   const float* __restrict__ W,
                                                   const ushort* __restrict__ Wbf,
                                                   float* __restrict__ C,
                                                   ushort* __restrict__ Cb,
                                                   int M, int N, int K, int ldC,
                                                   int act, int res, int swapg) {
  __shared__ ushort As[128 * 40];
  __shared__ ushort Ws[128 * 40];
  int bm, bn;
  if (swapg == 1) {
    bm = blockIdx.x * 128; bn = blockIdx.y * 128;
  } else {
    bm = blockIdx.y * 128; bn = blockIdx.x * 128;
  }
  const int tid = threadIdx.x;
  const int wave = tid >> 6, lane = tid & 63;
  const int wr = wave >> 1, wc = wave & 1;
  const int lr = lane & 15, lk = (lane >> 4) * 8;   // frag row-in-tile, k-base

  const int srow = tid >> 3;        // 0..31 (fp32 staging, 4 passes)
  const int scol = (tid & 7) * 4;   // 0..28
  const int grow = lane >> 2;       // 0..15 within wave's 16-row slab
  const int gcol = (lane & 3) * 8;  // ushort col 0,8,16,24

  const int PA = Abf ? 32 : 40;
  const int PW = Wbf ? 32 : 40;

  f32x4 acc[4][4] = {};

  for (int k0 = 0; k0 < K; k0 += 32) {
    if (Abf) {
#pragma unroll
      for (int p = 0; p < 2; ++p) {
        int rbase = p * 64 + wave * 16;
        gl_lds16(Abf + (size_t)(bm + rbase + grow) * K + k0 + gcol,
                 &As[rbase * 32]);
      }
    } else {
#pragma unroll
      for (int p = 0; p < 4; ++p) {
        int row = p * 32 + srow;
        float4 av = *reinterpret_cast<const float4*>(A + (size_t)(bm + row) * K + k0 + scol);
        uint2 aw; aw.x = pack2(av.x, av.y); aw.y = pack2(av.z, av.w);
        *reinterpret_cast<uint2*>(&As[row * 40 + scol]) = aw;
      }
    }
    if (Wbf) {
#pragma unroll
      for (int p = 0; p < 2; ++p) {
        int rbase = p * 64 + wave * 16;
        gl_lds16(Wbf + (size_t)(bn + rbase + grow) * K + k0 + gcol,
                 &Ws[rbase * 32]);
      }
    } else {
#pragma unroll
      for (int p = 0; p < 4; ++p) {
        int row = p * 32 + srow;
        float4 wv = *reinterpret_cast<const float4*>(W + (size_t)(bn + row) * K + k0 + scol);
        uint2 ww; ww.x = pack2(wv.x, wv.y); ww.y = pack2(wv.z, wv.w);
        *reinterpret_cast<uint2*>(&Ws[row * 40 + scol]) = ww;
      }
    }
    __syncthreads();
    short8v av[4], bv[4];
#pragma unroll
    for (int m = 0; m < 4; ++m)
      av[m] = *reinterpret_cast<const short8v*>(&As[(wr * 64 + m * 16 + lr) * PA + lk]);
#pragma unroll
    for (int n = 0; n < 4; ++n)
      bv[n] = *reinterpret_cast<const short8v*>(&Ws[(wc * 64 + n * 16 + lr) * PW + lk]);
#pragma unroll
    for (int m = 0; m < 4; ++m)
#pragma unroll
      for (int n = 0; n < 4; ++n)
        acc[m][n] = __builtin_amdgcn_mfma_f32_16x16x32_bf16(av[m], bv[n], acc[m][n], 0, 0, 0);
    __syncthreads();
  }

  const int rj = (lane >> 4) * 4;

  if (!Cb && !res) {
    // staged epilogue: As is dead after the k-loop; reuse as 16x128 fp32 tile
    float* Cs = (float*)As;           // 8192 B <= 10240 B
    const int rl = tid >> 5;          // 0..7
    const int cf = (tid & 31) * 4;    // 0..124
#pragma unroll
    for (int p = 0; p < 8; ++p) {
      __syncthreads();
      if (wr == (p >> 2)) {
        const int m = p & 3;
#pragma unroll
        for (int n = 0; n < 4; ++n)
#pragma unroll
          for (int j = 0; j < 4; ++j)
            Cs[(rj + j) * 128 + wc * 64 + n * 16 + lr] = acc[m][n][j];
      }
      __syncthreads();
#pragma unroll
      for (int rr = 0; rr < 2; ++rr) {
        int row_l = rr * 8 + rl;                 // 0..15
        float4 vv = *reinterpret_cast<const float4*>(&Cs[row_l * 128 + cf]);
        *reinterpret_cast<float4*>(&C[(size_t)(bm + p * 16 + row_l) * ldC + bn + cf]) = vv;
      }
    }
    return;
  }

#pragma unroll
  for (int m = 0; m < 4; ++m) {
    int rowb = bm + wr * 64 + m * 16 + rj;
#pragma unroll
    for (int n = 0; n < 4; ++n) {
      int col = bn + wc * 64 + n * 16 + lr;
#pragma unroll
      for (int j = 0; j < 4; ++j) {
        float v = acc[m][n][j];
        if (act == ACT_RELU2) { v = fmaxf(v, 0.f); v = v * v; }
        else if (act == ACT_SILU) { v = v / (1.f + expf(-v)); }
        if (Cb) {
          Cb[(size_t)(rowb + j) * ldC + col] = f2bf(v);
        } else {
          float* cp = C + (size_t)(rowb + j) * ldC + col;
          if (res) v += *cp;
          *cp = v;
        }
      }
    }
  }
}

// ---------------------------------------------------------------- merged QKV(+G) GEMM (bf16 A and W via gl_lds)
__global__ __launch_bounds__(256) void qkv_gemm_k(const ushort* __restrict__ Abf,
                                                  const ushort* __restrict__ W0,
                                                  const ushort* __restrict__ W1,
                                                  const ushort* __restrict__ W2,
                                                  const ushort* __restrict__ W3,
                                                  int p0, int p1, int p2,
                                                  float* __restrict__ C0,
                                                  float* __restrict__ C1,
                                                  float* __restrict__ C2,
                                                  float* __restrict__ C3,
                                                  int ldC0, int ldC1, int ldC2, int ldC3,
                                                  int cb0, int cb1, int cb2, int cb3,
                                                  int K) {
  __shared__ ushort As[128 * 32];
  __shared__ ushort Ws[128 * 32];
  const int pn = blockIdx.y;
  const ushort* W; float* C; int ldC; int colb; int dosilu = 0;
  if (pn < p0)      { W = W0 + (size_t)pn * 128 * K;        C = C0; ldC = ldC0; colb = cb0 + pn * 128; }
  else if (pn < p1) { W = W1 + (size_t)(pn - p0) * 128 * K; C = C1; ldC = ldC1; colb = cb1 + (pn - p0) * 128; }
  else if (pn < p2) { W = W2 + (size_t)(pn - p1) * 128 * K; C = C2; ldC = ldC2; colb = cb2 + (pn - p1) * 128; }
  else              { W = W3 + (size_t)(pn - p2) * 128 * K; C = C3; ldC = ldC3; colb = cb3 + (pn - p2) * 128; dosilu = 1; }
  const int bm = blockIdx.x * 128;
  const int tid = threadIdx.x;
  const int wave = tid >> 6, lane = tid & 63;
  const int wr = wave >> 1, wc = wave & 1;
  const int lr = lane & 15, lk = (lane >> 4) * 8;
  const int grow = lane >> 2;
  const int gcol = (lane & 3) * 8;

  f32x4 acc[4][4] = {};

  for (int k0 = 0; k0 < K; k0 += 32) {
#pragma unroll
    for (int p = 0; p < 2; ++p) {
      int rbase = p * 64 + wave * 16;
      gl_lds16(Abf + (size_t)(bm + rbase + grow) * K + k0 + gcol,
               &As[rbase * 32]);
      gl_lds16(W + (size_t)(rbase + grow) * K + k0 + gcol,
               &Ws[rbase * 32]);
    }
    __syncthreads();
    short8v av[4], bv[4];
#pragma unroll
    for (int m = 0; m < 4; ++m)
      av[m] = *reinterpret_cast<const short8v*>(&As[(wr * 64 + m * 16 + lr) * 32 + lk]);
#pragma unroll
    for (int n = 0; n < 4; ++n)
      bv[n] = *reinterpret_cast<const short8v*>(&Ws[(wc * 64 + n * 16 + lr) * 32 + lk]);
#pragma unroll
    for (int m = 0; m < 4; ++m)
#pragma unroll
      for (int n = 0; n < 4; ++n)
        acc[m][n] = __builtin_amdgcn_mfma_f32_16x16x32_bf16(av[m], bv[n], acc[m][n], 0, 0, 0);
    __syncthreads();
  }

  const int rj = (lane >> 4) * 4;
#pragma unroll
  for (int m = 0; m < 4; ++m) {
    int rowb = bm + wr * 64 + m * 16 + rj;
#pragma unroll
    for (int n = 0; n < 4; ++n) {
      int col = colb + wc * 64 + n * 16 + lr;
#pragma unroll
      for (int j = 0; j < 4; ++j) {
        float v = acc[m][n][j];
        if (dosilu) v = v / (1.f + expf(-v));
        C[(size_t)(rowb + j) * ldC + col] = v;
      }
    }
  }
}

// ---------------------------------------------------------------- fused alpha/beta sigmoid projection
__global__ __launch_bounds__(256) void ab_proj_k(const ushort* __restrict__ hb,
                                                 const float* __restrict__ za,
                                                 const float* __restrict__ zb,
                                                 float* __restrict__ alp,
                                                 float* __restrict__ bet) {
  const int tid = threadIdx.x;
  const int wave = tid >> 6, lane = tid & 63;
  const int l15 = lane & 15, lk = (lane >> 4) * 8;
  const int r0 = blockIdx.x * 64 + wave * 16;
  f32x4 accA = {}, accB = {};
  for (int k0 = 0; k0 < 1024; k0 += 32) {
    short8v a = *reinterpret_cast<const short8v*>(hb + (size_t)(r0 + l15) * 1024 + k0 + lk);
    const float* pa = za + l15 * 1024 + k0 + lk;
    const float* pb = zb + l15 * 1024 + k0 + lk;
    float4 xa = *reinterpret_cast<const float4*>(pa);
    float4 ya = *reinterpret_cast<const float4*>(pa + 4);
    float4 xb = *reinterpret_cast<const float4*>(pb);
    float4 yb = *reinterpret_cast<const float4*>(pb + 4);
    union { short8v v; uint u[4]; } ba, bb;
    ba.u[0] = pack2(xa.x, xa.y); ba.u[1] = pack2(xa.z, xa.w);
    ba.u[2] = pack2(ya.x, ya.y); ba.u[3] = pack2(ya.z, ya.w);
    bb.u[0] = pack2(xb.x, xb.y); bb.u[1] = pack2(xb.z, xb.w);
    bb.u[2] = pack2(yb.x, yb.y); bb.u[3] = pack2(yb.z, yb.w);
    accA = __builtin_amdgcn_mfma_f32_16x16x32_bf16(a, ba.v, accA, 0, 0, 0);
    accB = __builtin_amdgcn_mfma_f32_16x16x32_bf16(a, bb.v, accB, 0, 0, 0);
  }
  const int rj = (lane >> 4) * 4;
#pragma unroll
  for (int j = 0; j < 4; ++j) {
    int row = r0 + rj + j;
    alp[(size_t)row * 16 + l15] = 1.f / (1.f + expf(-accA[j]));
    bet[(size_t)row * 16 + l15] = 1.f / (1.f + expf(-accB[j]));
  }
}

// ---------------------------------------------------------------- l2norm (+gain) (+rope) on rows of 64
// outb != nullptr: emit bf16 to outb and skip the fp32 writeback (consumer
// reads only bf16; identical f2bf rounding to the old cvt_bf pass).
__global__ __launch_bounds__(256) void l2n_rope_k(float* __restrict__ P, int NH,
                                                  const float* __restrict__ gain,
                                                  const float* __restrict__ cosT,
                                                  const float* __restrict__ sinT,
                                                  int do_rope,
                                                  ushort* __restrict__ outb) {
  int row = blockIdx.x * 4 + (threadIdx.x >> 6);
  int lane = threadIdx.x & 63;
  size_t idx = (size_t)row * 64 + lane;
  float val = P[idx];
  float ss = val * val;
#pragma unroll
  for (int m = 1; m < 64; m <<= 1) ss += __shfl_xor(ss, m, 64);
  val = val / fmaxf(sqrtf(ss), 1e-6f);
  int hh = row % NH;
  int t = (row / NH) & (TT - 1);
  if (gain) val *= gain[hh];
  if (do_rope) {
    float pr = __shfl_xor(val, 32, 64);
    int jj = lane & 31;
    float c = cosT[t * 32 + jj];
    float s = sinT[t * 32 + jj];
    val = (lane < 32) ? (val * c + pr * s) : (val * c - pr * s);
  }
  if (outb) outb[idx] = f2bf(val);
  else P[idx] = val;
}

// ---------------------------------------------------------------- MFMA flash attention (bf16 pre-converted K/V; bf16 out)
__global__ __launch_bounds__(256) void attn_mfma_k(const float* __restrict__ Q,
                                                   const ushort* __restrict__ Kbb,
                                                   const ushort* __restrict__ Vtb,
                                                   ushort* __restrict__ Ob16) {
  __shared__ ushort Ks[64 * 72];
  __shared__ ushort Vt[64 * 72];
  __shared__ ushort Ps[4][16 * 72];

  const int q0 = blockIdx.x * 64;
  const int bh = blockIdx.y;
  const int b = bh >> 4, hh = bh & 15;
  const int kvh = hh >> 2;
  const int tid = threadIdx.x;
  const int wave = tid >> 6, lane = tid & 63;
  const int l15 = lane & 15, l16 = lane >> 4;   // 0..15 / 0..3
  const int rj = l16 * 4;

  const int qrs = HH * 64;    // 1024
  const int krs = KVH * 64;   // 256
  const float* Qb = Q + (size_t)b * TT * qrs + hh * 64;
  const ushort* Kb = Kbb + (size_t)b * TT * krs + kvh * 64;
  const ushort* Vb = Vtb + (size_t)(b * KVH + kvh) * 64 * TT;
  ushort* Ob = Ob16 + (size_t)b * TT * qrs + hh * 64;

  short8v qa[2];
  {
    const float* qp = Qb + (size_t)(q0 + wave * 16 + l15) * qrs + l16 * 8;
#pragma unroll
    for (int dblk = 0; dblk < 2; ++dblk) {
      float4 x = *reinterpret_cast<const float4*>(qp + dblk * 32);
      float4 y = *reinterpret_cast<const float4*>(qp + dblk * 32 + 4);
      union { short8v v; uint u[4]; } tmp;
      tmp.u[0] = pack2(x.x, x.y); tmp.u[1] = pack2(x.z, x.w);
      tmp.u[2] = pack2(y.x, y.y); tmp.u[3] = pack2(y.z, y.w);
      qa[dblk] = tmp.v;
    }
  }

  short8v ones;
  { union { short8v v; uint u[4]; } t;
    t.u[0] = t.u[1] = t.u[2] = t.u[3] = 0x3F803F80u; ones = t.v; }

  f32x4 o[4] = {};
  f32x4 denom = {};

  const int srow = tid >> 2;          // 0..63 (key for Ks, d for Vt)
  const int sc16 = (tid & 3) * 16;    // 16-ushort column base

  for (int kc = 0; kc <= q0; kc += 64) {
    __syncthreads();
    {
      const ushort* kp = Kb + (size_t)(kc + srow) * krs + sc16;
      *reinterpret_cast<short8v*>(&Ks[srow * 72 + sc16]) =
          *reinterpret_cast<const short8v*>(kp);
      *reinterpret_cast<short8v*>(&Ks[srow * 72 + sc16 + 8]) =
          *reinterpret_cast<const short8v*>(kp + 8);
      const ushort* vp = Vb + (size_t)srow * TT + kc + sc16;
      *reinterpret_cast<short8v*>(&Vt[srow * 72 + sc16]) =
          *reinterpret_cast<const short8v*>(vp);
      *reinterpret_cast<short8v*>(&Vt[srow * 72 + sc16 + 8]) =
          *reinterpret_cast<const short8v*>(vp + 8);
    }
    __syncthreads();

    // S = Q @ K^T (16q x 64k)
    f32x4 s[4];
#pragma unroll
    for (int kb = 0; kb < 4; ++kb) {
      short8v k0 = *reinterpret_cast<const short8v*>(&Ks[(kb * 16 + l15) * 72 + l16 * 8]);
      short8v k1 = *reinterpret_cast<const short8v*>(&Ks[(kb * 16 + l15) * 72 + 32 + l16 * 8]);
      f32x4 z = {};
      z = __builtin_amdgcn_mfma_f32_16x16x32_bf16(qa[0], k0, z, 0, 0, 0);
      s[kb] = __builtin_amdgcn_mfma_f32_16x16x32_bf16(qa[1], k1, z, 0, 0, 0);
    }

    // causal mask + exp -> Ps bf16
    const int qg = q0 + wave * 16 + rj;
#pragma unroll
    for (int kb = 0; kb < 4; ++kb) {
      int key = kc + kb * 16 + l15;
#pragma unroll
      for (int j = 0; j < 4; ++j) {
        float p = (key <= qg + j) ? __expf(s[kb][j]) : 0.f;
        Ps[wave][(rj + j) * 72 + kb * 16 + l15] = f2bf(p);
      }
    }

    short8v pa0 = *reinterpret_cast<const short8v*>(&Ps[wave][l15 * 72 + l16 * 8]);
    short8v pa1 = *reinterpret_cast<const short8v*>(&Ps[wave][l15 * 72 + 32 + l16 * 8]);

    f32x4 dz = {};
    dz = __builtin_amdgcn_mfma_f32_16x16x32_bf16(pa0, ones, dz, 0, 0, 0);
    dz = __builtin_amdgcn_mfma_f32_16x16x32_bf16(pa1, ones, dz, 0, 0, 0);
    denom += dz;

#pragma unroll
    for (int db = 0; db < 4; ++db) {
      short8v v0 = *reinterpret_cast<const short8v*>(&Vt[(db * 16 + l15) * 72 + l16 * 8]);
      short8v v1 = *reinterpret_cast<const short8v*>(&Vt[(db * 16 + l15) * 72 + 32 + l16 * 8]);
      o[db] = __builtin_amdgcn_mfma_f32_16x16x32_bf16(pa0, v0, o[db], 0, 0, 0);
      o[db] = __builtin_amdgcn_mfma_f32_16x16x32_bf16(pa1, v1, o[db], 0, 0, 0);
    }
  }

  const int qg = q0 + wave * 16 + rj;
#pragma unroll
  for (int j = 0; j < 4; ++j) {
    float inv = 1.0f / denom[j];
    ushort* op = Ob + (size_t)(qg + j) * qrs;
#pragma unroll
    for (int db = 0; db < 4; ++db) op[db * 16 + l15] = f2bf(o[db][j] * inv);
  }
}

// ---------------------------------------------------------------- causal depthwise conv (CK=4) + silu + split
__global__ __launch_bounds__(256) void conv_k(const float* __restrict__ X,
                                              const float* __restrict__ Wc,
                                              float* __restrict__ Qo,
                                              float* __restrict__ Ko,
                                              float* __restrict__ Vo) {
  int idx = blockIdx.x * 256 + threadIdx.x;   // B*T*3072 exact
  int c = idx % 3072;
  int rest = idx / 3072;
  int t = rest & (TT - 1);
  int b = rest >> 10;
  const float* w = Wc + c * 4;
  float acc = 0.f;
#pragma unroll
  for (int j = 0; j < 4; ++j) {
    int tt = t - 3 + j;
    if (tt >= 0) acc += w[j] * X[((size_t)(b * TT + tt)) * 3072 + c];
  }
  float y = acc / (1.f + expf(-acc));   // silu
  int which = c >> 10, cc = c & 1023;
  float* dst = (which == 0) ? Qo : ((which == 1) ? Ko : Vo);
  dst[((size_t)(b * TT + t)) * 1024 + cc] = y;
}

// ---------------------------------------------------------------- GDN segmented scan
__global__ __launch_bounds__(256) void gdn_p1_k(const float* __restrict__ Kg,
                                                const float* __restrict__ Vg,
                                                const float* __restrict__ Al,
                                                const float* __restrict__ Be,
                                                float* __restrict__ Aseg,
                                                float* __restrict__ Useg) {
  __shared__ float Kl[2][CH * 64];
  __shared__ float Vl[2][CH * 64];
  __shared__ float As_[2][CH];
  __shared__ float Bs_[2][CH];

  const int seg = blockIdx.x;            // 0..7
  const int bh = blockIdx.y;             // 0..31
  const int basis = (blockIdx.z == 0);
  const int b = bh >> 4, hh = bh & 15;
  const int tid = threadIdx.x;
  const int wave = tid >> 6;
  const int lane = tid & 63;
  const int vloc = lane >> 2;
  const int dgrp = lane & 3;
  const int d0 = dgrp * 16;
  const int v = wave * 16 + vloc;

  const size_t base = (size_t)b * TT * 1024 + hh * 64 + (size_t)seg * SEGL * 1024;
  const size_t ab0 = (size_t)b * TT * HH + hh + (size_t)seg * SEGL * HH;

  const int s_step = tid >> 4;
  const int s_col = (tid & 15) * 4;

  float S[16];
#pragma unroll
  for (int i = 0; i < 16; ++i) S[i] = (basis && (d0 + i == v)) ? 1.f : 0.f;

  float4 kst[2], vst[2];
  float ast = 0.f, bst = 0.f;

#define ISSUE(c0)                                                              \
  {                                                                            \
    _Pragma("unroll") for (int p = 0; p < 2; ++p) {                            \
      int st = p * 16 + s_step;                                                \
      size_t off = base + (size_t)((c0) + st) * 1024 + s_col;                  \
      kst[p] = *reinterpret_cast<const float4*>(Kg + off);                     \
      if (!basis) vst[p] = *reinterpret_cast<const float4*>(Vg + off);         \
    }                                                                          \
    if (tid < CH) ast = Al[ab0 + (size_t)((c0) + tid) * HH];                   \
    else if (tid < 2 * CH) bst = Be[ab0 + (size_t)((c0) + tid - CH) * HH];     \
  }

#define WRITE(ib)                                                              \
  {                                                                            \
    _Pragma("unroll") for (int p = 0; p < 2; ++p) {                            \
      int st = p * 16 + s_step;                                                \
      *reinterpret_cast<float4*>(&Kl[ib][st * 64 + s_col]) = kst[p];           \
      if (!basis) *reinterpret_cast<float4*>(&Vl[ib][st * 64 + s_col]) = vst[p];\
    }                                                                          \
    if (tid < CH) As_[ib][tid] = ast;                                          \
    else if (tid < 2 * CH) Bs_[ib][tid - CH] = bst;                            \
  }

#define LOADL(KX, VX, AX, BX, ib, tt)                                          \
  {                                                                            \
    const float* kp = &Kl[ib][(tt) * 64 + d0];                                 \
    _Pragma("unroll") for (int i = 0; i < 4; ++i) {                            \
      float4 kv = *reinterpret_cast<const float4*>(kp + i * 4);                \
      KX[4 * i] = kv.x; KX[4 * i + 1] = kv.y;                                  \
      KX[4 * i + 2] = kv.z; KX[4 * i + 3] = kv.w;                              \
    }                                                                          \
    VX = basis ? 0.f : Vl[ib][(tt) * 64 + v];                                  \
    AX = As_[ib][(tt)];                                                        \
    BX = Bs_[ib][(tt)];                                                        \
  }

#define STEP(KX, VX, AX, BX)                                                   \
  {                                                                            \
    float t0 = 0.f, t1 = 0.f, t2 = 0.f, t3 = 0.f;                              \
    _Pragma("unroll") for (int i = 0; i < 16; i += 4) {                        \
      t0 += KX[i] * S[i];                                                      \
      t1 += KX[i + 1] * S[i + 1];                                              \
      t2 += KX[i + 2] * S[i + 2];                                              \
      t3 += KX[i + 3] * S[i + 3];                                              \
    }                                                                          \
    float ks = qadd4((t0 + t1) + (t2 + t3));                                   \
    float cin = VX - AX * BX * ks;                                             \
    _Pragma("unroll") for (int i = 0; i < 16; ++i)                             \
      S[i] = AX * S[i] + cin * KX[i];                                          \
  }

  float kA[16], kB[16];
  float vA, aA, btA, vB, aB, btB;

  const int NC = SEGL / CH;   // 4 chunks
  ISSUE(0);
  WRITE(0);
  __syncthreads();
  ISSUE(CH);
  for (int cnk = 0; cnk < NC; ++cnk) {
    const int ib = cnk & 1;
    LOADL(kA, vA, aA, btA, ib, 0);
    for (int t = 0; t < CH; t += 2) {
      LOADL(kB, vB, aB, btB, ib, t + 1);
      STEP(kA, vA, aA, btA);
      if (t + 2 < CH) LOADL(kA, vA, aA, btA, ib, t + 2);
      STEP(kB, vB, aB, btB);
    }
    if (cnk + 1 < NC) {
      WRITE(ib ^ 1);
      __syncthreads();
      if (cnk + 2 < NC) ISSUE((cnk + 2) * CH);
    }
  }
#undef ISSUE
#undef WRITE
#undef LOADL
#undef STEP

  float* dst = (basis ? Aseg : Useg) + (size_t)(bh * 8 + seg) * 4096;
#pragma unroll
  for (int i = 0; i < 16; ++i) dst[(d0 + i) * 64 + v] = S[i];
}

__global__ __launch_bounds__(256) void gdn_p2_k(const float* __restrict__ Aseg,
                                                const float* __restrict__ Useg,
                                                float* __restrict__ S0) {
  __shared__ float Sc[4096];
  const int bh = blockIdx.x;
  const int tid = threadIdx.x;
  for (int i = tid; i < 4096; i += 256) Sc[i] = 0.f;
  __syncthreads();
  const int dr = tid >> 2;         // 0..63 (row)
  const int v4 = (tid & 3) * 16;   // col base
  for (int s = 0; s < 8; ++s) {
    for (int i = tid; i < 4096; i += 256) S0[(size_t)(bh * 8 + s) * 4096 + i] = Sc[i];
    if (s == 7) break;
    const float* Arow = Aseg + (size_t)(bh * 8 + s) * 4096 + dr * 64;
    const float* Up = Useg + (size_t)(bh * 8 + s) * 4096 + dr * 64 + v4;
    float acc[16];
#pragma unroll
    for (int i = 0; i < 16; ++i) acc[i] = Up[i];
    for (int j = 0; j < 64; ++j) {
      float a = Arow[j];
      const float* sr = &Sc[j * 64 + v4];
#pragma unroll
      for (int i = 0; i < 16; ++i) acc[i] += a * sr[i];
    }
    __syncthreads();
#pragma unroll
    for (int i = 0; i < 16; ++i) Sc[dr * 64 + v4 + i] = acc[i];
    __syncthreads();
  }
}

__global__ __launch_bounds__(256) void gdn_p3_k(const float* __restrict__ Qg,
                                                const float* __restrict__ Kg,
                                                const float* __restrict__ Vg,
                                                const float* __restrict__ Al,
                                                const float* __restrict__ Be,
                                                const float* __restrict__ S0,
                                                float* __restrict__ Og) {
  __shared__ float Kl[2][CH * 64];
  __shared__ float Ql[2][CH * 64];
  __shared__ float Vl[2][CH * 64];
  __shared__ float As_[2][CH];
  __shared__ float Bs_[2][CH];

  const int seg = blockIdx.x;            // 0..7
  const int bh = blockIdx.y;             // 0..31
  const int b = bh >> 4, hh = bh & 15;
  const int tid = threadIdx.x;
  const int wave = tid >> 6;
  const int lane = tid & 63;
  const int vloc = lane >> 2;
  const int dgrp = lane & 3;
  const int d0 = dgrp * 16;
  const int v = wave * 16 + vloc;

  const size_t base = (size_t)b * TT * 1024 + hh * 64 + (size_t)seg * SEGL * 1024;
  const size_t ab0 = (size_t)b * TT * HH + hh + (size_t)seg * SEGL * HH;

  const int s_step = tid >> 4;
  const int s_col = (tid & 15) * 4;

  float S[16];
  {
    const float* sp = S0 + (size_t)(bh * 8 + seg) * 4096;
#pragma unroll
    for (int i = 0; i < 16; ++i) S[i] = sp[(d0 + i) * 64 + v];
  }

  float4 kst[2], qst[2], vst[2];
  float ast = 0.f, bst = 0.f;

#define ISSUE(c0)                                                              \
  {                                                                            \
    _Pragma("unroll") for (int p = 0; p < 2; ++p) {                            \
      int st = p * 16 + s_step;                                                \
      size_t off = base + (size_t)((c0) + st) * 1024 + s_col;                  \
      kst[p] = *reinterpret_cast<const float4*>(Kg + off);                     \
      qst[p] = *reinterpret_cast<const float4*>(Qg + off);                     \
      vst[p] = *reinterpret_cast<const float4*>(Vg + off);                     \
    }                                                                          \
    if (tid < CH) ast = Al[ab0 + (size_t)((c0) + tid) * HH];                   \
    else if (tid < 2 * CH) bst = Be[ab0 + (size_t)((c0) + tid - CH) * HH];     \
  }

#define WRITE(ib)                                                              \
  {                                                                            \
    _Pragma("unroll") for (int p = 0; p < 2; ++p) {                            \
      int st = p * 16 + s_step;                                                \
      *reinterpret_cast<float4*>(&Kl[ib][st * 64 + s_col]) = kst[p];           \
      *reinterpret_cast<float4*>(&Ql[ib][st * 64 + s_col]) = qst[p];           \
      *reinterpret_cast<float4*>(&Vl[ib][st * 64 + s_col]) = vst[p];           \
    }                                                                          \
    if (tid < CH) As_[ib][tid] = ast;                                          \
    else if (tid < 2 * CH) Bs_[ib][tid - CH] = bst;                            \
  }

#define LOADL(KX, QX, VX, AX, BX, ib, tt)                                      \
  {                                                                            \
    const float* kp = &Kl[ib][(tt) * 64 + d0];                                 \
    const float* qp = &Ql[ib][(tt) * 64 + d0];                                 \
    _Pragma("unroll") for (int i = 0; i < 4; ++i) {                            \
      float4 kv = *reinterpret_cast<const float4*>(kp + i * 4);                \
      KX[4 * i] = kv.x; KX[4 * i + 1] = kv.y;                                  \
      KX[4 * i + 2] = kv.z; KX[4 * i + 3] = kv.w;                              \
      float4 qv = *reinterpret_cast<const float4*>(qp + i * 4);                \
      QX[4 * i] = qv.x; QX[4 * i + 1] = qv.y;                                  \
      QX[4 * i + 2] = qv.z; QX[4 * i + 3] = qv.w;                              \
    }                                                                          \
    VX = Vl[ib][(tt) * 64 + v];                                                \
    AX = As_[ib][(tt)];                                                        \
    BX = Bs_[ib][(tt)];                                                        \
  }

#define STEP(KX, QX, VX, AX, BX, gt)                                           \
  {                                                                            \
    float t0 = 0.f, t1 = 0.f, t2 = 0.f, t3 = 0.f;                              \
    _Pragma("unroll") for (int i = 0; i < 16; i += 4) {                        \
      t0 += KX[i] * S[i];                                                      \
      t1 += KX[i + 1] * S[i + 1];                                              \
      t2 += KX[i + 2] * S[i + 2];                                              \
      t3 += KX[i + 3] * S[i + 3];                                              \
    }                                                                          \
    float ks = qadd4((t0 + t1) + (t2 + t3));                                   \
    float cin = VX - AX * BX * ks;                                             \
    float o0 = 0.f, o1 = 0.f, o2 = 0.f, o3 = 0.f;                              \
    _Pragma("unroll") for (int i = 0; i < 16; i += 4) {                        \
      S[i] = AX * S[i] + cin * KX[i];               o0 += QX[i] * S[i];        \
      S[i + 1] = AX * S[i + 1] + cin * KX[i + 1];   o1 += QX[i + 1] * S[i + 1];\
      S[i + 2] = AX * S[i + 2] + cin * KX[i + 2];   o2 += QX[i + 2] * S[i + 2];\
      S[i + 3] = AX * S[i + 3] + cin * KX[i + 3];   o3 += QX[i + 3] * S[i + 3];\
    }                                                                          \
    float o = qadd4((o0 + o1) + (o2 + o3));                                    \
    if (dgrp == 0) Og[base + (size_t)(gt) * 1024 + v] = o;                     \
  }

  float kA[16], qA[16], kB[16], qB[16];
  float vA, aA, btA, vB, aB, btB;

  const int NC = SEGL / CH;   // 4 chunks
  ISSUE(0);
  WRITE(0);
  __syncthreads();
  ISSUE(CH);
  for (int cnk = 0; cnk < NC; ++cnk) {
    const int ib = cnk & 1;
    LOADL(kA, qA, vA, aA, btA, ib, 0);
    for (int t = 0; t < CH; t += 2) {
      LOADL(kB, qB, vB, aB, btB, ib, t + 1);
      STEP(kA, qA, vA, aA, btA, cnk * CH + t);
      if (t + 2 < CH) LOADL(kA, qA, vA, aA, btA, ib, t + 2);
      STEP(kB, qB, vB, aB, btB, cnk * CH + t + 1);
    }
    if (cnk + 1 < NC) {
      WRITE(ib ^ 1);
      __syncthreads();
      if (cnk + 2 < NC) ISSUE((cnk + 2) * CH);
    }
  }
#undef ISSUE
#undef WRITE
#undef LOADL
#undef STEP
}

// ---------------------------------------------------------------- rmsnorm over 64 * gate -> bf16 out
__global__ __launch_bounds__(256) void rms64_mul_k(const float* __restrict__ O,
                                                   const float* __restrict__ G,
                                                   ushort* __restrict__ Ob) {
  int row = blockIdx.x * 4 + (threadIdx.x >> 6);
  int lane = threadIdx.x & 63;
  size_t idx = (size_t)row * 64 + lane;
  float val = O[idx];
  float ss = val * val;
#pragma unroll
  for (int m = 1; m < 64; m <<= 1) ss += __shfl_xor(ss, m, 64);
  float sc = rsqrtf(ss * (1.0f / 64.0f) + 1e-6f);
  Ob[idx] = f2bf(val * sc * G[idx]);
}

// ---------------------------------------------------------------- host-side launch
static inline void gemm(hipStream_t s, const float* A, const ushort* Abf,
                        const float* W, const ushort* Wbf, float* C, ushort* Cb,
                        int M, int N, int K, int ldC, int act, int res) {
  int swap = (N >= 2048) ? 1 : 0;
  dim3 g = swap ? dim3(M / 128, N / 128) : dim3(N / 128, M / 128);
  mfma_gemm_k<<<g, 256, 0, s>>>(A, Abf, W, Wbf, C, Cb, M, N, K, ldC, act, res, swap);
}

extern "C" void kernel_launch(void* const* d_in, const int* in_sizes, int n_in,
                              void* d_out, int out_size, void* d_ws, size_t ws_size,
                              hipStream_t stream) {
  const int*   tokens = (const int*)d_in[0];
  const float* emb    = (const float*)d_in[1];
  const float* aw_q   = (const float*)d_in[2];
  const float* aw_k   = (const float*)d_in[3];
  const float* aw_v   = (const float*)d_in[4];
  const float* aw_o   = (const float*)d_in[5];
  const float* a_gain = (const float*)d_in[6];
  const float* a_m1   = (const float*)d_in[7];
  const float* a_m2   = (const float*)d_in[8];
  const float* g_wq   = (const float*)d_in[9];
  const float* g_wk   = (const float*)d_in[10];
  const float* g_wv   = (const float*)d_in[11];
  const float* g_wa   = (const float*)d_in[12];
  const float* g_wb   = (const float*)d_in[13];
  const float* g_wg   = (const float*)d_in[14];
  const float* g_wo   = (const float*)d_in[15];
  const float* g_conv = (const float*)d_in[16];
  const float* g_m1   = (const float*)d_in[17];
  const float* g_m2   = (const float*)d_in[18];

  const int M = BB * TT;  // 2048

  // ---- d_out scratch (fully rewritten by the final logits GEMM; nothing here read during it)
  float* outF = (float*)d_out;
  ushort* midb = (ushort*)outF;              // [0, 4194304) floats as bf16 M*DFF
  float* scanA = outF + 4194304;             // 1048576 (gdn A_seg)
  float* scanU = scanA + 1048576;            // 1048576 (gdn U_seg)
  float* scanS = scanU + 1048576;            // 1048576 (gdn S0)
  ushort* kbb = (ushort*)(outF + 7340032);   // 524288 ushorts (bf16 attn K)
  ushort* vtb = kbb + 524288;                // 524288 ushorts (bf16 attn V^T)
  float* qkv  = outF + 8388608;              // [8388608, 14680064)  B*T*3072
  ushort* hb  = (ushort*)(outF + 14680064);  // [14680064, 15728640) bf16 h

  // bf16 weight cache [15728640, 40370176)
  ushort* wtb = (ushort*)(outF + 15728640);
  ushort* awq_b = wtb;                 // 2097152 (both layers)
  ushort* awk_b = awq_b + 2097152;     // 524288
  ushort* awv_b = awk_b + 524288;      // 524288
  ushort* awo_b = awv_b + 524288;      // 2097152
  ushort* am1_b = awo_b + 2097152;     // 8388608
  ushort* am2_b = am1_b + 8388608;     // 8388608
  ushort* gwq_b = am2_b + 8388608;     // 2097152
  ushort* gwk_b = gwq_b + 2097152;     // 2097152
  ushort* gwv_b = gwk_b + 2097152;     // 2097152
  ushort* gwg_b = gwv_b + 2097152;     // 2097152
  ushort* gwo_b = gwg_b + 2097152;     // 2097152
  ushort* gm1_b = gwo_b + 2097152;     // 8388608
  ushort* gm2_b = gm1_b + 8388608;     // 8388608  (ends at float 40370176)

  // per-layer activations [40370176, ...); qgb/ogb are M*1024 = 2097152 ushorts each
  float* qb   = outF + 40370176;             // 2097152 -> ends 42467328
  float* kb   = qb + 2097152;                // 524288  -> ends 42991616
  float* vb   = kb + 524288;                 // 524288  -> ends 43515904
  float* qg   = vb + 524288;                 // 2097152 -> ends 45613056
  float* kg   = qg + 2097152;                // 2097152 -> ends 47710208 (contiguous after qg)
  float* vg   = kg + 2097152;                // 2097152 -> ends 49807360
  float* og   = vg + 2097152;                // 2097152 -> ends 51904512
  float* gb   = og + 2097152;                // 2097152 -> ends 54001664
  ushort* qgb = (ushort*)(gb + 2097152);     // 2097152 ushorts -> float [54001664, 55050240)
  ushort* ogb = qgb + 2097152;               // 2097152 ushorts -> float [55050240, 56098816)
  float* x    = outF + 56098816;             // 2097152 -> ends 58195968
  float* alp  = outF + 58195968;             // 32768
  float* bet  = alp + 32768;                 // 32768
  float* cosT = bet + 32768;                 // 32768
  float* sinT = cosT + 32768;                // 32768 -> ends 58327040

  // ---- ws: {embb, hbL} = 71,303,168 B (within the 71,827,456 B footprint
  // proven safe by rounds 1-19).
  ushort* embb = (ushort*)d_ws;                 // VV*DD ushorts (64 MiB)
  ushort* hbL  = embb + (size_t)VV * DD;        // M*DD ushorts (4 MB)

  rope_tab_k<<<128, 256, 0, stream>>>(cosT, sinT);
  embed_k<<<M, 256, 0, stream>>>(tokens, emb, x);
  cvt_bf_k<<<2048, 256, 0, stream>>>(emb, embb, (VV * DD) / 8);

  // pre-convert all layer weights to bf16 (one-time per launch)
  cvt_bf_k<<<1024, 256, 0, stream>>>(aw_q, awq_b, 2097152 / 8);
  cvt_bf_k<<<512, 256, 0, stream>>>(aw_k, awk_b, 524288 / 8);
  cvt_bf_k<<<512, 256, 0, stream>>>(aw_v, awv_b, 524288 / 8);
  cvt_bf_k<<<1024, 256, 0, stream>>>(aw_o, awo_b, 2097152 / 8);
  cvt_bf_k<<<2048, 256, 0, stream>>>(a_m1, am1_b, 8388608 / 8);
  cvt_bf_k<<<2048, 256, 0, stream>>>(a_m2, am2_b, 8388608 / 8);
  cvt_bf_k<<<1024, 256, 0, stream>>>(g_wq, gwq_b, 2097152 / 8);
  cvt_bf_k<<<1024, 256, 0, stream>>>(g_wk, gwk_b, 2097152 / 8);
  cvt_bf_k<<<1024, 256, 0, stream>>>(g_wv, gwv_b, 2097152 / 8);
  cvt_bf_k<<<1024, 256, 0, stream>>>(g_wg, gwg_b, 2097152 / 8);
  cvt_bf_k<<<1024, 256, 0, stream>>>(g_wo, gwo_b, 2097152 / 8);
  cvt_bf_k<<<2048, 256, 0, stream>>>(g_m1, gm1_b, 8388608 / 8);
  cvt_bf_k<<<2048, 256, 0, stream>>>(g_m2, gm2_b, 8388608 / 8);

  for (int i = 0; i < 2; ++i) {
    const float* za = g_wa + (size_t)i * 16 * 1024;
    const float* zb = g_wb + (size_t)i * 16 * 1024;
    const float* zc = g_conv + (size_t)i * 3072 * 4;
    const ushort* wq_b = awq_b + (size_t)i * 1048576;
    const ushort* wk_b = awk_b + (size_t)i * 262144;
    const ushort* wv_b = awv_b + (size_t)i * 262144;
    const ushort* wo_b = awo_b + (size_t)i * 1048576;
    const ushort* m1_b = am1_b + (size_t)i * 4194304;
    const ushort* m2_b = am2_b + (size_t)i * 4194304;
    const ushort* zq_b = gwq_b + (size_t)i * 1048576;
    const ushort* zk_b = gwk_b + (size_t)i * 1048576;
    const ushort* zv_b = gwv_b + (size_t)i * 1048576;
    const ushort* zg_b = gwg_b + (size_t)i * 1048576;
    const ushort* zo_b = gwo_b + (size_t)i * 1048576;
    const ushort* n1_b = gm1_b + (size_t)i * 4194304;
    const ushort* n2_b = gm2_b + (size_t)i * 4194304;

    // ---------------- attention block ----------------
    rmsnorm_k<<<M, 256, 0, stream>>>(x, nullptr, hb);
    qkv_gemm_k<<<dim3(M / 128, 12), 256, 0, stream>>>(
        hb, wq_b, wk_b, wv_b, nullptr, 8, 10, 12,
        qb, kb, vb, nullptr, 1024, 256, 256, 0, 0, 0, 0, 0, 1024);
    l2n_rope_k<<<(M * HH) / 4, 256, 0, stream>>>(qb, HH, a_gain + (size_t)i * 16, cosT, sinT, 1, nullptr);
    l2n_rope_k<<<(M * KVH) / 4, 256, 0, stream>>>(kb, KVH, nullptr, cosT, sinT, 1, kbb);
    cvt_vt_k<<<2048, 256, 0, stream>>>(vb, vtb);
    attn_mfma_k<<<dim3(TT / 64, BB * HH), 256, 0, stream>>>(qb, kbb, vtb, qgb);
    gemm(stream, nullptr, qgb, nullptr, wo_b, x, nullptr, M, 1024, 1024, 1024, ACT_NONE, 1);
    rmsnorm_k<<<M, 256, 0, stream>>>(x, nullptr, hb);
    gemm(stream, nullptr, hb, nullptr, m1_b, nullptr, midb, M, DFF, 1024, DFF, ACT_RELU2, 0);
    gemm(stream, nullptr, midb, nullptr, m2_b, x, nullptr, M, 1024, DFF, 1024, ACT_NONE, 1);

    // ---------------- GDN block ----------------
    rmsnorm_k<<<M, 256, 0, stream>>>(x, nullptr, hb);
    qkv_gemm_k<<<dim3(M / 128, 32), 256, 0, stream>>>(
        hb, zq_b, zk_b, zv_b, zg_b, 8, 16, 24,
        qkv, qkv, qkv, gb, 3072, 3072, 3072, 1024, 0, 1024, 2048, 0, 1024);
    conv_k<<<(M * 3072) / 256, 256, 0, stream>>>(qkv, zc, qg, kg, vg);
    // qg and kg are contiguous: one fused l2norm launch over both (no gain/rope)
    l2n_rope_k<<<(2 * M * HH) / 4, 256, 0, stream>>>(qg, HH, nullptr, nullptr, nullptr, 0, nullptr);
    ab_proj_k<<<M / 64, 256, 0, stream>>>(hb, za, zb, alp, bet);
    gdn_p1_k<<<dim3(8, BB * HH, 2), 256, 0, stream>>>(kg, vg, alp, bet, scanA, scanU);
    gdn_p2_k<<<BB * HH, 256, 0, stream>>>(scanA, scanU, scanS);
    gdn_p3_k<<<dim3(8, BB * HH), 256, 0, stream>>>(qg, kg, vg, alp, bet, scanS, og);
    rms64_mul_k<<<(M * HH) / 4, 256, 0, stream>>>(og, gb, ogb);
    gemm(stream, nullptr, ogb, nullptr, zo_b, x, nullptr, M, 1024, 1024, 1024, ACT_NONE, 1);
    rmsnorm_k<<<M, 256, 0, stream>>>(x, nullptr, hb);
    gemm(stream, nullptr, hb, nullptr, n1_b, nullptr, midb, M, DFF, 1024, DFF, ACT_RELU2, 0);
    gemm(stream, nullptr, midb, nullptr, n2_b, x, nullptr, M, 1024, DFF, 1024, ACT_NONE, 1);
  }

  // ---------------- final logits: A = hbL (bf16, ws), W = embb (bf16, ws).
  rmsnorm_k<<<M, 256, 0, stream>>>(x, nullptr, hbL);
  gemm(stream, nullptr, hbL, nullptr, embb, outF, nullptr, M, VV, 1024, VV, ACT_NONE, 0);
}